// Round 5
// baseline (809.563 us; speedup 1.0000x reference)
//
#include <hip/hip_runtime.h>
#include <hip/hip_fp8.h>

typedef unsigned short u16;
typedef unsigned char u8;
typedef __attribute__((ext_vector_type(8))) __bf16 bfrag;
typedef long long f8frag;
typedef __attribute__((ext_vector_type(4))) float f32x4;

static __device__ __forceinline__ f32x4 MFMA(bfrag a, bfrag b, f32x4 c) {
  return __builtin_amdgcn_mfma_f32_16x16x32_bf16(a, b, c, 0, 0, 0);
}
static __device__ __forceinline__ f32x4 MFMA8(f8frag a, f8frag b, f32x4 c) {
  return __builtin_amdgcn_mfma_f32_16x16x32_fp8_fp8(a, b, c, 0, 0, 0);
}

// float -> bf16 (RNE)
static __device__ __forceinline__ u16 f2b(float f) {
  union { float f; unsigned u; } v; v.f = f;
  unsigned r = (v.u + 0x7fffu + ((v.u >> 16) & 1u)) >> 16;
  return (u16)r;
}
// float -> fp8 e4m3 via HW cvt (gfx950: OCP e4m3fn)
static __device__ __forceinline__ u8 f2e4m3(float f) {
  return (u8)(__builtin_amdgcn_cvt_pk_fp8_f32(f, f, 0, false) & 0xff);
}
static __device__ __forceinline__ unsigned pk4_e4m3(float a, float b, float c, float d) {
  int p = __builtin_amdgcn_cvt_pk_fp8_f32(a, b, 0, false);
  p = __builtin_amdgcn_cvt_pk_fp8_f32(c, d, p, true);
  return (unsigned)p;
}
static __device__ __forceinline__ float ssig(float x) { return 1.f / (1.f + __expf(-x)); }
static __device__ __forceinline__ float stanh(float x) { return 1.f - 2.f / (__expf(2.f * x) + 1.f); }

// barrier that waits only on LDS traffic (no vmcnt store-ack drain)
#define LDS_BARRIER() asm volatile("s_waitcnt lgkmcnt(0)\ns_barrier" ::: "memory")

// ---------------------------------------------------------------------------
// prep (layouts unchanged from v10)
// ---------------------------------------------------------------------------
struct PrepArgs {
  const float *x, *W1, *W2, *W3, *Wh1, *Wc1, *Wx1, *Wh2, *Wc2, *Wx2;
  const float *rWih, *rWhh, *rbih, *rbhh, *pWih, *pWhh, *pbih, *pbhh;
  u16 *Xbf, *W1b, *W2b, *W3b, *Wh1b, *Wc1b, *Wx1b, *Wh2b, *Wc2b, *Wx2b;
  u16 *WcatR;
  u8 *WsS, *pWsS, *pWhhS;
  float *rbR, *pbR;
};

__global__ __launch_bounds__(256) void prep(PrepArgs p) {
  const int tid0 = blockIdx.x * 256 + threadIdx.x;
  const int stride = gridDim.x * 256;
  switch (blockIdx.y) {
    case 0: for (int i = tid0; i < 131072; i += stride) p.Xbf[i] = f2b(p.x[i]); break;
    case 1: for (int i = tid0; i < 65536;  i += stride) p.W1b[i] = f2b(p.W1[i]); break;
    case 2: for (int i = tid0; i < 262144; i += stride) p.W2b[i] = f2b(p.W2[i]); break;
    case 3: for (int i = tid0; i < 262144; i += stride) p.W3b[i] = f2b(p.W3[i]); break;
    case 4: for (int i = tid0; i < 262144; i += stride) p.Wh1b[i] = f2b(p.Wh1[i]); break;
    case 5: for (int i = tid0; i < 262144; i += stride) p.Wc1b[i] = f2b(p.Wc1[i]); break;
    case 6: for (int i = tid0; i < 262144; i += stride) p.Wx1b[i] = f2b(p.Wx1[i]); break;
    case 7: for (int i = tid0; i < 131072; i += stride) p.Wh2b[i] = f2b(p.Wh2[i]); break;
    case 8: for (int i = tid0; i < 131072; i += stride) p.Wc2b[i] = f2b(p.Wc2[i]); break;
    case 9: for (int i = tid0; i < 131072; i += stride) p.Wx2b[i] = f2b(p.Wx2[i]); break;
    case 10: // step-0 concat weights (bf16, gate-retiled)
      for (int i = tid0; i < 262144; i += stride) {
        int n = i >> 8, k = i & 255;
        int srow = (((n >> 4) & 3) << 8) + ((n >> 6) << 4) + (n & 15);
        p.WcatR[n * 512 + k] = f2b(p.rWih[srow * 256 + k]);
        p.WcatR[n * 512 + 256 + k] = f2b(p.rWhh[srow * 256 + k]);
      }
      break;
    case 11:
      for (int i = tid0; i < 1024; i += stride) {
        int srow = (((i >> 4) & 3) << 8) + ((i >> 6) << 4) + (i & 15);
        p.rbR[i] = p.rbih[srow] + p.rbhh[srow];
      }
      break;
    case 12: // pred x-weights fp8, swizzled-contiguous
      for (int i = tid0; i < 32768; i += stride) {
        int j = i & 7, lane = (i >> 3) & 63, kt = (i >> 9) & 7, w = i >> 12;
        int n = w * 16 + (lane & 15);
        int srow = ((n & 3) << 5) + (n >> 2);
        int k = kt * 32 + ((lane >> 4) & 3) * 8 + j;
        p.pWsS[i] = f2e4m3(p.pWih[srow * 256 + k]);
      }
      break;
    case 13: // pred h-weights fp8, swizzled-contiguous
      for (int i = tid0; i < 4096; i += stride) {
        int j = i & 7, lane = (i >> 3) & 63, w = i >> 9;
        int n = w * 16 + (lane & 15);
        int srow = ((n & 3) << 5) + (n >> 2);
        int k = ((lane >> 4) & 3) * 8 + j;
        p.pWhhS[i] = f2e4m3(p.pWhh[srow * 32 + k]);
      }
      break;
    case 14:
      for (int i = tid0; i < 128; i += stride) {
        int srow = ((i & 3) << 5) + (i >> 2);
        p.pbR[i] = p.pbih[srow] + p.pbhh[srow];
      }
      break;
    case 15: // decode combined weights fp8, swizzled-contiguous stream layout
      for (int i = tid0; i < 262144; i += stride) {
        int j = i & 7, lane = (i >> 3) & 63, kt = (i >> 9) & 7;
        int gate = (i >> 12) & 3, g16 = i >> 14;
        int srow = gate * 256 + g16 * 16 + (lane & 15);
        int k = kt * 32 + ((lane >> 4) & 3) * 8 + j;
        p.WsS[i] = f2e4m3(p.rWih[srow * 256 + k] + p.rWhh[srow * 256 + k]);
      }
      break;
  }
}

// ---------------------------------------------------------------------------
// gemm_act: Y[1024,N] = act(X[1024,K] @ W[N,K]^T + bias), bf16 in, fp32 acc.
// ---------------------------------------------------------------------------
__global__ __launch_bounds__(256) void gemm_act(
    const u16* __restrict__ X, const u16* __restrict__ W,
    const float* __restrict__ bias,
    u16* __restrict__ Yb, float* __restrict__ Yf,
    int K, int ldo, int coloff, int leaky) {
  const int rt = blockIdx.x, ct = blockIdx.y;
  const int lane = threadIdx.x & 63, wave = threadIdx.x >> 6;
  const int m15 = lane & 15, q = lane >> 4, kq = q * 8;
  const int row = rt * 64 + wave * 16 + m15;
  f32x4 acc[4] = {};
  const u16* xp = X + (size_t)row * K + kq;
  for (int k0 = 0; k0 < K; k0 += 32) {
    bfrag a = *(const bfrag*)(xp + k0);
#pragma unroll
    for (int nt = 0; nt < 4; nt++) {
      const u16* wp = W + (size_t)(ct * 64 + nt * 16 + m15) * K + k0 + kq;
      acc[nt] = MFMA(a, *(const bfrag*)wp, acc[nt]);
    }
  }
#pragma unroll
  for (int nt = 0; nt < 4; nt++) {
    int col = ct * 64 + nt * 16 + m15;
    float bv = bias[col];
#pragma unroll
    for (int r = 0; r < 4; r++) {
      int orow = rt * 64 + wave * 16 + q * 4 + r;
      float v = acc[nt][r] + bv;
      if (leaky) v = v >= 0.f ? v : 0.2f * v;
      if (Yb) Yb[(size_t)orow * ldo + coloff + col] = f2b(v);
      else    Yf[(size_t)orow * ldo + coloff + col] = v;
    }
  }
}

// ---------------------------------------------------------------------------
// decode_step: step 0 only (K=512 concat input, bf16), gate-retiled columns.
// ---------------------------------------------------------------------------
__global__ __launch_bounds__(256) void decode_step(
    const u16* __restrict__ A, const u16* __restrict__ W,
    const float* __restrict__ rb,
    float* __restrict__ C, u16* __restrict__ Hout, int K) {
  __shared__ float g[64][128];
  const int rt = blockIdx.x, cg = blockIdx.y;
  const int lane = threadIdx.x & 63, wave = threadIdx.x >> 6;
  const int m15 = lane & 15, q = lane >> 4, kq = q * 8;
  const int row = rt * 64 + wave * 16 + m15;
  f32x4 acc[8] = {};
  const u16* ap = A + (size_t)row * K + kq;
  for (int k0 = 0; k0 < K; k0 += 32) {
    bfrag a = *(const bfrag*)(ap + k0);
#pragma unroll
    for (int nt = 0; nt < 8; nt++) {
      const u16* wp = W + (size_t)(cg * 128 + nt * 16 + m15) * K + k0 + kq;
      acc[nt] = MFMA(a, *(const bfrag*)wp, acc[nt]);
    }
  }
#pragma unroll
  for (int nt = 0; nt < 8; nt++)
#pragma unroll
    for (int r = 0; r < 4; r++)
      g[wave * 16 + q * 4 + r][nt * 16 + m15] = acc[nt][r];
  __syncthreads();
  for (int t = threadIdx.x; t < 2048; t += 256) {
    int rl = t >> 5, hc = t & 31;
    int grow = rt * 64 + rl, gcol = cg * 32 + hc;
    int base = ((hc >> 4) << 6) + (hc & 15);
    float gi = g[rl][base +  0] + rb[cg * 128 + base +  0];
    float gf = g[rl][base + 16] + rb[cg * 128 + base + 16];
    float gg = g[rl][base + 32] + rb[cg * 128 + base + 32];
    float go = g[rl][base + 48] + rb[cg * 128 + base + 48];
    size_t ci = (size_t)grow * 256 + gcol;
    float c = C[ci];
    float cn = ssig(gf) * c + ssig(gi) * stanh(gg);
    float hn = ssig(go) * stanh(cn);
    C[ci] = cn;
    Hout[ci] = f2b(hn);
  }
}

// ---------------------------------------------------------------------------
// v11: three stream-ordered kernels.
// R4 diagnosis: FETCH_SIZE 19MB (60% of hG re-fetched from HBM) => producers
// run FAR ahead; the consumer (pred+softmax+out) is, and always was, the
// critical path (explains v6..v10 invariance; the only win, v7, removed a
// phase-2 LDS transpose). The consumer chain is latency-bound: flag spin,
// cross-L2 hG loads, 10 dependent __shfl (ds_bpermute) softmax, per-step
// vmcnt(0) drains of the out stores.
// v11: (a) softmax is TERMINAL -> lift it out of the recurrence into a
// fully-parallel elementwise kernel (in-place on d_out); (b) no flags: three
// stream-ordered kernels decode_h -> pred_y -> softmax_out; (c) pred_y
// stages 4 h-steps (16KB contiguous) per chunk into swizzled LDS; (d) all
// in-loop barriers are lgkmcnt-only (LDS_BARRIER) -- no vmcnt store drains.
// ---------------------------------------------------------------------------
#define PIN_A8(A) asm volatile("" : "+a"(A[0]), "+a"(A[1]), "+a"(A[2]), "+a"(A[3]), \
                                    "+a"(A[4]), "+a"(A[5]), "+a"(A[6]), "+a"(A[7]))
#define PIN_V8(A) asm volatile("" : "+v"(A[0]), "+v"(A[1]), "+v"(A[2]), "+v"(A[3]), \
                                    "+v"(A[4]), "+v"(A[5]), "+v"(A[6]), "+v"(A[7]))

// ---- decode_h: 64 blocks x 1024, h recurrence only, publishes hG ----
__global__ __attribute__((amdgpu_flat_work_group_size(1024, 1024), amdgpu_waves_per_eu(4, 4)))
void decode_h(
    const u8* __restrict__ WsS,     // [262144] swizzled fp8 decode weights
    const float* __restrict__ rb,   // rbR [1024]
    const float* __restrict__ C0,   // CB  [1024][256] (c after step 0)
    const u16* __restrict__ H0,     // h_0 [1024][256] bf16
    u8* __restrict__ hG) {          // [64][128][4096] fp8 h stream
  __shared__ __align__(16) u8 hbuf8[2][16][272];  // h ping-pong (swizzled)
  __shared__ float rbL[1024];
  const int tid = threadIdx.x;
  const int w = tid >> 6, lane = tid & 63;
  const int m15 = lane & 15, q = lane >> 4;
  const int km = m15 & 3;
  const int b = blockIdx.x;
  const int rowg = b * 16;
  rbL[tid] = rb[tid];
  // h_0 -> fp8 into hbuf8[0] (swizzled) and hG[b][0]
  {
    int r = tid >> 6, c = (tid & 63) * 4;
    const u16* src = H0 + (size_t)(rowg + r) * 256 + c;
    float f0, f1, f2, f3;
    { union { float f; unsigned u; } v; v.u = (unsigned)src[0] << 16; f0 = v.f; }
    { union { float f; unsigned u; } v; v.u = (unsigned)src[1] << 16; f1 = v.f; }
    { union { float f; unsigned u; } v; v.u = (unsigned)src[2] << 16; f2 = v.f; }
    { union { float f; unsigned u; } v; v.u = (unsigned)src[3] << 16; f3 = v.f; }
    unsigned hv = pk4_e4m3(f0, f1, f2, f3);
    *(unsigned*)(&hbuf8[0][r][0] + (c ^ ((r & 3) << 5))) = hv;
    *(unsigned*)(hG + (size_t)b * 524288 + r * 256 + c) = hv;
  }
  // c state: (batch m15, hcols w*16+q*4..+3)
  f32x4 cst = *(const f32x4*)(C0 + (size_t)(rowg + m15) * 256 + w * 16 + q * 4);
  // all 4 gate weight sets resident: 32 frags = 64 AGPRs
  const u8* wsb = WsS + (size_t)w * 16384 + lane * 8;
  f8frag Wv0[8], Wv1[8], Wv2[8], Wv3[8];
#pragma unroll
  for (int kt = 0; kt < 8; kt++) {
    Wv0[kt] = *(const f8frag*)(wsb + kt * 512);
    Wv1[kt] = *(const f8frag*)(wsb + 4096 + kt * 512);
    Wv2[kt] = *(const f8frag*)(wsb + 8192 + kt * 512);
    Wv3[kt] = *(const f8frag*)(wsb + 12288 + kt * 512);
  }
  PIN_A8(Wv0); PIN_A8(Wv1); PIN_A8(Wv2); PIN_A8(Wv3);
  const int hwr = m15 * 272 + ((w ^ (2 * km)) * 16 + q * 4);
  __syncthreads();

  for (int s = 1; s < 128; s++) {
    PIN_A8(Wv0); PIN_A8(Wv1); PIN_A8(Wv2); PIN_A8(Wv3);
    const u8* h8 = &hbuf8[(s - 1) & 1][0][0] + m15 * 272 + q * 8;
    f32x4 ai  = *(const f32x4*)&rbL[w * 64 +  0 + q * 4];
    f32x4 af_ = *(const f32x4*)&rbL[w * 64 + 16 + q * 4];
    f32x4 ag  = *(const f32x4*)&rbL[w * 64 + 32 + q * 4];
    f32x4 ao  = *(const f32x4*)&rbL[w * 64 + 48 + q * 4];
#pragma unroll
    for (int kt = 0; kt < 8; kt++) {
      f8frag a8 = *(const f8frag*)(h8 + ((kt ^ km) << 5));
      ai  = MFMA8(Wv0[kt], a8, ai);
      af_ = MFMA8(Wv1[kt], a8, af_);
      ag  = MFMA8(Wv2[kt], a8, ag);
      ao  = MFMA8(Wv3[kt], a8, ao);
    }
    float hn[4];
#pragma unroll
    for (int r = 0; r < 4; r++) {
      float cn = ssig(af_[r]) * cst[r] + ssig(ai[r]) * stanh(ag[r]);
      hn[r] = ssig(ao[r]) * stanh(cn);
      cst[r] = cn;
    }
    unsigned hv = pk4_e4m3(hn[0], hn[1], hn[2], hn[3]);
    *(unsigned*)(&hbuf8[s & 1][0][0] + hwr) = hv;
    *(unsigned*)(hG + (size_t)b * 524288 + s * 4096 + m15 * 256 + w * 16 + q * 4) = hv;
    // only LDS hazards cross this barrier; hG store-acks float freely
    LDS_BARRIER();
  }
}

// ---- pred_y: 64 blocks x 512 (8 waves), chunked hG->LDS, raw y to d_out ----
__global__ __launch_bounds__(512, 2) void pred_y(
    const u8* __restrict__ hG,      // [64][128][4096]
    const u8* __restrict__ pWsS,    // [32768] swizzled fp8 pred x-weights
    const u8* __restrict__ pWhhS,   // [4096] swizzled fp8 pred h-weights
    const float* __restrict__ pb,   // pbR [128]
    float* __restrict__ y) {        // [1024][128][32] raw gates (= d_out)
  __shared__ __align__(16) u8 stage[4][16][272];  // 17 KB chunk stage (swz)
  __shared__ __align__(16) u8 hp8[2][16][40];
  __shared__ float ysC[4][16][36];
  const int tid = threadIdx.x;      // 0..511
  const int w = tid >> 6, lane = tid & 63;
  const int m15 = lane & 15, q = lane >> 4;
  const int km = m15 & 3;
  const int b = blockIdx.x, rowg = b * 16;
  for (int i = tid; i < 2 * 16 * 40; i += 512) (&hp8[0][0][0])[i] = 0;
  // pred weights resident (18 VGPRs; budget 128 via launch_bounds(512,2))
  const u8* pwsb = pWsS + (size_t)w * 4096 + lane * 8;
  f8frag pbv[8];
#pragma unroll
  for (int kt = 0; kt < 8; kt++) pbv[kt] = *(const f8frag*)(pwsb + kt * 512);
  f8frag phw = *(const f8frag*)(pWhhS + (size_t)w * 512 + lane * 8);
  PIN_V8(pbv);
  asm volatile("" : "+v"(phw));
  const f32x4 pbias = *(const f32x4*)(pb + w * 16 + q * 4);
  float cp = 0.f;
  const u8* hGb = hG + (size_t)b * 524288;
  __syncthreads();

  for (int cs = 0; cs < 32; cs++) {
    // stage 4 steps (16 KB contiguous) into swizzled LDS
    {
      const int o0 = tid * 32;
#pragma unroll
      for (int hh = 0; hh < 2; hh++) {
        int o = o0 + hh * 16;
        int si = o >> 12, r = (o >> 8) & 15, c = o & 255;
        int4 v = *(const int4*)(hGb + (size_t)cs * 16384 + o);
        *(int4*)(&stage[si][r][0] + (c ^ ((r & 3) << 5))) = v;
      }
    }
    LDS_BARRIER();   // stage visible (load->LDS deps already vmcnt-waited)
#pragma unroll
    for (int si = 0; si < 4; si++) {
      const int s = cs * 4 + si;
      const u8* xr8 = &stage[si][0][0] + m15 * 272 + q * 8;
      f32x4 pacc = pbias;
#pragma unroll
      for (int kt = 0; kt < 8; kt++) {
        f8frag pav = *(const f8frag*)(xr8 + ((kt ^ km) << 5));
        pacc = MFMA8(pbv[kt], pav, pacc);
      }
      f8frag pah = *(const f8frag*)(&hp8[s & 1][m15][q * 8]);
      pacc = MFMA8(phw, pah, pacc);
      // lane (m15,q) holds gates i,f,g,o of (batch m15, predcol w*4+q)
      float cn = ssig(pacc[1]) * cp + ssig(pacc[0]) * stanh(pacc[2]);
      float hn_p = ssig(pacc[3]) * stanh(cn);
      cp = cn;
      hp8[(s + 1) & 1][m15][w * 4 + q] = f2e4m3(hn_p);
      ysC[si][m15][w * 4 + q] = hn_p;
      LDS_BARRIER();   // hp8 cross-wave ordering (cheap: no vmem pending)
    }
    // flush raw y chunk (8 KB) to global; acks drain lazily
    {
      int si = tid >> 7, r = (tid >> 3) & 15, j4 = (tid & 7) * 4;
      float4 v = *(const float4*)&ysC[si][r][j4];
      *(float4*)(y + (size_t)(rowg + r) * 4096 + (cs * 4 + si) * 32 + j4) = v;
    }
    LDS_BARRIER();   // ysC consumed before next chunk overwrites
  }
}

// ---- softmax_out: fully parallel terminal softmax/sigmoid, in-place ----
__global__ __launch_bounds__(256) void softmax_out(float* __restrict__ y) {
  const int t = blockIdx.x * 256 + threadIdx.x;   // 0..131071 = (batch,step)
  float* p = y + (size_t)t * 32;
  float v[32];
  float4* pv = (float4*)p;
#pragma unroll
  for (int i = 0; i < 8; i++) {
    float4 x = pv[i];
    v[i * 4 + 0] = x.x; v[i * 4 + 1] = x.y; v[i * 4 + 2] = x.z; v[i * 4 + 3] = x.w;
  }
  float m = v[0];
#pragma unroll
  for (int j = 1; j < 31; j++) m = fmaxf(m, v[j]);
  float tot = 0.f;
  float e[31];
#pragma unroll
  for (int j = 0; j < 31; j++) { e[j] = __expf(v[j] - m); tot += e[j]; }
  float inv = 1.f / tot;
#pragma unroll
  for (int j = 0; j < 31; j++) v[j] = e[j] * inv;
  v[31] = ssig(v[31]);
#pragma unroll
  for (int i = 0; i < 8; i++) {
    float4 x; x.x = v[i * 4 + 0]; x.y = v[i * 4 + 1]; x.z = v[i * 4 + 2]; x.w = v[i * 4 + 3];
    pv[i] = x;
  }
}

// ---------------------------------------------------------------------------
extern "C" void kernel_launch(void* const* d_in, const int* in_sizes, int n_in,
                              void* d_out, int out_size, void* d_ws, size_t ws_size,
                              hipStream_t stream) {
  (void)in_sizes; (void)n_in; (void)out_size; (void)ws_size;
  const float* x    = (const float*)d_in[0];
  const float* W1   = (const float*)d_in[1];
  const float* b1   = (const float*)d_in[2];
  const float* W2   = (const float*)d_in[3];
  const float* b2   = (const float*)d_in[4];
  const float* W3   = (const float*)d_in[5];
  const float* b3   = (const float*)d_in[6];
  const float* Wh1  = (const float*)d_in[7];
  const float* bh1  = (const float*)d_in[8];
  const float* Wh2  = (const float*)d_in[9];
  const float* bh2  = (const float*)d_in[10];
  const float* Wc1  = (const float*)d_in[11];
  const float* bc1  = (const float*)d_in[12];
  const float* Wc2  = (const float*)d_in[13];
  const float* bc2  = (const float*)d_in[14];
  const float* Wx1  = (const float*)d_in[15];
  const float* bx1  = (const float*)d_in[16];
  const float* Wx2  = (const float*)d_in[17];
  const float* bx2  = (const float*)d_in[18];
  const float* rWih = (const float*)d_in[19];
  const float* rWhh = (const float*)d_in[20];
  const float* rbih = (const float*)d_in[21];
  const float* rbhh = (const float*)d_in[22];
  const float* pWih = (const float*)d_in[23];
  const float* pWhh = (const float*)d_in[24];
  const float* pbih = (const float*)d_in[25];
  const float* pbhh = (const float*)d_in[26];

  char* w = (char*)d_ws;
  auto alloc = [&](size_t bytes) -> char* {
    char* p = w;
    w += (bytes + 255) & ~(size_t)255;
    return p;
  };
  u16* Xbf  = (u16*)alloc(1024 * 128 * 2);
  u16* T1   = (u16*)alloc(1024 * 512 * 2);
  u16* T2   = (u16*)alloc(1024 * 512 * 2);
  u16* T3   = (u16*)alloc(1024 * 512 * 2);
  u16* TH   = (u16*)alloc(1024 * 512 * 2);
  u16* TC   = (u16*)alloc(1024 * 512 * 2);
  u16* TX   = (u16*)alloc(1024 * 512 * 2);
  u16* X0H  = (u16*)alloc(1024 * 512 * 2);  // cols 0..255 = x0, 256..511 = h
  float* CB = (float*)alloc(1024 * 256 * 4);
  u16* OUTS0= (u16*)alloc(1024 * 256 * 2);  // h_0 only
  u16* W1b  = (u16*)alloc(512 * 128 * 2);
  u16* W2b  = (u16*)alloc(512 * 512 * 2);
  u16* W3b  = (u16*)alloc(512 * 512 * 2);
  u16* Wh1b = (u16*)alloc(512 * 512 * 2);
  u16* Wc1b = (u16*)alloc(512 * 512 * 2);
  u16* Wx1b = (u16*)alloc(512 * 512 * 2);
  u16* Wh2b = (u16*)alloc(256 * 512 * 2);
  u16* Wc2b = (u16*)alloc(256 * 512 * 2);
  u16* Wx2b = (u16*)alloc(256 * 512 * 2);
  u16* WcatR= (u16*)alloc(1024 * 512 * 2);
  u8*  WsS  = (u8*)alloc(262144);
  u8*  pWsS = (u8*)alloc(32768);
  u8*  pWhhS= (u8*)alloc(4096);
  float* rbR = (float*)alloc(1024 * 4);
  float* pbR = (float*)alloc(128 * 4);
  u8*  hG   = (u8*)alloc((size_t)64 * 128 * 4096);   // 32 MB fp8 h stream

  PrepArgs pa;
  pa.x = x; pa.W1 = W1; pa.W2 = W2; pa.W3 = W3; pa.Wh1 = Wh1; pa.Wc1 = Wc1; pa.Wx1 = Wx1;
  pa.Wh2 = Wh2; pa.Wc2 = Wc2; pa.Wx2 = Wx2;
  pa.rWih = rWih; pa.rWhh = rWhh; pa.rbih = rbih; pa.rbhh = rbhh;
  pa.pWih = pWih; pa.pWhh = pWhh; pa.pbih = pbih; pa.pbhh = pbhh;
  pa.Xbf = Xbf; pa.W1b = W1b; pa.W2b = W2b; pa.W3b = W3b; pa.Wh1b = Wh1b;
  pa.Wc1b = Wc1b; pa.Wx1b = Wx1b; pa.Wh2b = Wh2b; pa.Wc2b = Wc2b; pa.Wx2b = Wx2b;
  pa.WcatR = WcatR;
  pa.WsS = WsS; pa.pWsS = pWsS; pa.pWhhS = pWhhS;
  pa.rbR = rbR; pa.pbR = pbR;
  prep<<<dim3(32, 16), 256, 0, stream>>>(pa);

  // MLP + heads
  gemm_act<<<dim3(16, 8), 256, 0, stream>>>(Xbf, W1b, b1, T1, nullptr, 128, 512, 0, 1);
  gemm_act<<<dim3(16, 8), 256, 0, stream>>>(T1, W2b, b2, T2, nullptr, 512, 512, 0, 1);
  gemm_act<<<dim3(16, 8), 256, 0, stream>>>(T2, W3b, b3, T3, nullptr, 512, 512, 0, 1);
  gemm_act<<<dim3(16, 8), 256, 0, stream>>>(T3, Wh1b, bh1, TH, nullptr, 512, 512, 0, 1);
  gemm_act<<<dim3(16, 8), 256, 0, stream>>>(T3, Wc1b, bc1, TC, nullptr, 512, 512, 0, 1);
  gemm_act<<<dim3(16, 8), 256, 0, stream>>>(T3, Wx1b, bx1, TX, nullptr, 512, 512, 0, 1);
  gemm_act<<<dim3(16, 4), 256, 0, stream>>>(TH, Wh2b, bh2, X0H, nullptr, 512, 512, 256, 0); // h
  gemm_act<<<dim3(16, 4), 256, 0, stream>>>(TC, Wc2b, bc2, nullptr, CB, 512, 256, 0, 0);    // c (fp32)
  gemm_act<<<dim3(16, 4), 256, 0, stream>>>(TX, Wx2b, bx2, X0H, nullptr, 512, 512, 0, 0);   // x0

  // decode step 0, then the three stream-ordered stages
  decode_step<<<dim3(16, 8), 256, 0, stream>>>(X0H, WcatR, rbR, CB, OUTS0, 512);
  decode_h<<<64, 1024, 0, stream>>>(WsS, rbR, CB, OUTS0, hG);
  pred_y<<<64, 512, 0, stream>>>(hG, pWsS, pWhhS, pbR, (float*)d_out);
  softmax_out<<<512, 256, 0, stream>>>((float*)d_out);
}

// Round 6
// 518.737 us; speedup vs baseline: 1.5606x; 1.5606x over previous
//
#include <hip/hip_runtime.h>
#include <hip/hip_fp8.h>

typedef unsigned short u16;
typedef unsigned char u8;
typedef __attribute__((ext_vector_type(8))) __bf16 bfrag;
typedef long long f8frag;
typedef __attribute__((ext_vector_type(4))) float f32x4;

static __device__ __forceinline__ f32x4 MFMA(bfrag a, bfrag b, f32x4 c) {
  return __builtin_amdgcn_mfma_f32_16x16x32_bf16(a, b, c, 0, 0, 0);
}
static __device__ __forceinline__ f32x4 MFMA8(f8frag a, f8frag b, f32x4 c) {
  return __builtin_amdgcn_mfma_f32_16x16x32_fp8_fp8(a, b, c, 0, 0, 0);
}

// float -> bf16 (RNE)
static __device__ __forceinline__ u16 f2b(float f) {
  union { float f; unsigned u; } v; v.f = f;
  unsigned r = (v.u + 0x7fffu + ((v.u >> 16) & 1u)) >> 16;
  return (u16)r;
}
// float -> fp8 e4m3 via HW cvt (gfx950: OCP e4m3fn)
static __device__ __forceinline__ u8 f2e4m3(float f) {
  return (u8)(__builtin_amdgcn_cvt_pk_fp8_f32(f, f, 0, false) & 0xff);
}
static __device__ __forceinline__ unsigned pk4_e4m3(float a, float b, float c, float d) {
  int p = __builtin_amdgcn_cvt_pk_fp8_f32(a, b, 0, false);
  p = __builtin_amdgcn_cvt_pk_fp8_f32(c, d, p, true);
  return (unsigned)p;
}
// R5 finding: 1.f/x without fast-math emits the full IEEE div sequence
// (~8 ops). v_rcp_f32 is 1 instr, ~1e-5 rel err << fp8 noise.
static __device__ __forceinline__ float rcp(float x) { return __builtin_amdgcn_rcpf(x); }
static __device__ __forceinline__ float ssig(float x) {
  float E = __expf(x);
  return E * rcp(1.f + E);
}
static __device__ __forceinline__ float stanh(float x) {
  float E = __expf(2.f * x);
  return 1.f - 2.f * rcp(E + 1.f);
}
// Shared-denominator LSTM cell: cn = sig(f)c + sig(i)tanh(g), hn = sig(o)tanh(cn)
// = [c*Ef*QR + Ei*P*(Eg-1)] / (P*QR), Eo(Ec-1)/[(1+Eo)(Ec+1)].
// 7 trans (5 exp + 2 rcp) per value vs 10 trans + 5 IEEE divs before.
static __device__ __forceinline__ float2 lstm2(float gi, float gf, float gg,
                                               float go, float c) {
  float Ei = __expf(gi), Ef = __expf(gf), Eg = __expf(2.f * gg), Eo = __expf(go);
  float P = 1.f + Ef, Q = 1.f + Ei, R = 1.f + Eg;
  float QR = Q * R;
  float num = c * Ef * QR + Ei * P * (Eg - 1.f);
  float cn = num * rcp(P * QR);
  float Ec = __expf(2.f * cn);
  float hn = Eo * (Ec - 1.f) * rcp((1.f + Eo) * (Ec + 1.f));
  return make_float2(hn, cn);
}

// barrier that waits only on LDS traffic (no vmcnt store-ack drain)
#define LDS_BARRIER() asm volatile("s_waitcnt lgkmcnt(0)\ns_barrier" ::: "memory")
#define PIN_A8(A) asm volatile("" : "+a"(A[0]), "+a"(A[1]), "+a"(A[2]), "+a"(A[3]), \
                                    "+a"(A[4]), "+a"(A[5]), "+a"(A[6]), "+a"(A[7]))
#define PIN_V8(A) asm volatile("" : "+v"(A[0]), "+v"(A[1]), "+v"(A[2]), "+v"(A[3]), \
                                    "+v"(A[4]), "+v"(A[5]), "+v"(A[6]), "+v"(A[7]))

// ---------------------------------------------------------------------------
// prep. GEMM weights (cases 1-9) now emitted in FRAGMENT-STREAM layout:
//   Wst[(((ct*4+nt)*KT + kt)*64 + lane)*8 + j] = W[ct*64+nt*16+(lane&15)]
//                                                 [kt*32+((lane>>4)&3)*8+j]
// so a wave's (ct,nt,kt) fragment load is one contiguous 1KB block
// (old row-major layout touched 16 cache lines per load instruction).
// Case 15 (decode) / 12,13 (pred) keep the fp8 stream layout.
// ---------------------------------------------------------------------------
struct PrepArgs {
  const float *x, *W1, *W2, *W3, *Wh1, *Wc1, *Wx1, *Wh2, *Wc2, *Wx2;
  const float *rWih, *rWhh, *rbih, *rbhh, *pWih, *pWhh, *pbih, *pbhh;
  u16 *Xbf, *W1b, *W2b, *W3b, *Wh1b, *Wc1b, *Wx1b, *Wh2b, *Wc2b, *Wx2b;
  u16 *WcatR;
  u8 *WsS, *pWsS, *pWhhS;
  float *rbR, *pbR;
};

// stream emit helper: KT = K/32
static __device__ __forceinline__ void emit_stream(u16* dst, const float* src,
                                                   int i, int K, int ktbits) {
  int j = i & 7, lane = (i >> 3) & 63;
  int kt = (i >> 9) & ((1 << ktbits) - 1);
  int nt = (i >> (9 + ktbits)) & 3;
  int ct = i >> (11 + ktbits);
  int srow = ct * 64 + nt * 16 + (lane & 15);
  int scol = kt * 32 + ((lane >> 4) & 3) * 8 + j;
  dst[i] = f2b(src[srow * K + scol]);
}

__global__ __launch_bounds__(256) void prep(PrepArgs p) {
  const int tid0 = blockIdx.x * 256 + threadIdx.x;
  const int stride = gridDim.x * 256;
  switch (blockIdx.y) {
    case 0: for (int i = tid0; i < 131072; i += stride) p.Xbf[i] = f2b(p.x[i]); break;
    case 1: for (int i = tid0; i < 65536;  i += stride) emit_stream(p.W1b, p.W1, i, 128, 2); break;
    case 2: for (int i = tid0; i < 262144; i += stride) emit_stream(p.W2b, p.W2, i, 512, 4); break;
    case 3: for (int i = tid0; i < 262144; i += stride) emit_stream(p.W3b, p.W3, i, 512, 4); break;
    case 4: for (int i = tid0; i < 262144; i += stride) emit_stream(p.Wh1b, p.Wh1, i, 512, 4); break;
    case 5: for (int i = tid0; i < 262144; i += stride) emit_stream(p.Wc1b, p.Wc1, i, 512, 4); break;
    case 6: for (int i = tid0; i < 262144; i += stride) emit_stream(p.Wx1b, p.Wx1, i, 512, 4); break;
    case 7: for (int i = tid0; i < 131072; i += stride) emit_stream(p.Wh2b, p.Wh2, i, 512, 4); break;
    case 8: for (int i = tid0; i < 131072; i += stride) emit_stream(p.Wc2b, p.Wc2, i, 512, 4); break;
    case 9: for (int i = tid0; i < 131072; i += stride) emit_stream(p.Wx2b, p.Wx2, i, 512, 4); break;
    case 10: // step-0 concat weights (bf16, gate-retiled, row-major: decode_step only)
      for (int i = tid0; i < 262144; i += stride) {
        int n = i >> 8, k = i & 255;
        int srow = (((n >> 4) & 3) << 8) + ((n >> 6) << 4) + (n & 15);
        p.WcatR[n * 512 + k] = f2b(p.rWih[srow * 256 + k]);
        p.WcatR[n * 512 + 256 + k] = f2b(p.rWhh[srow * 256 + k]);
      }
      break;
    case 11:
      for (int i = tid0; i < 1024; i += stride) {
        int srow = (((i >> 4) & 3) << 8) + ((i >> 6) << 4) + (i & 15);
        p.rbR[i] = p.rbih[srow] + p.rbhh[srow];
      }
      break;
    case 12: // pred x-weights fp8, swizzled-contiguous
      for (int i = tid0; i < 32768; i += stride) {
        int j = i & 7, lane = (i >> 3) & 63, kt = (i >> 9) & 7, w = i >> 12;
        int n = w * 16 + (lane & 15);
        int srow = ((n & 3) << 5) + (n >> 2);
        int k = kt * 32 + ((lane >> 4) & 3) * 8 + j;
        p.pWsS[i] = f2e4m3(p.pWih[srow * 256 + k]);
      }
      break;
    case 13: // pred h-weights fp8, swizzled-contiguous
      for (int i = tid0; i < 4096; i += stride) {
        int j = i & 7, lane = (i >> 3) & 63, w = i >> 9;
        int n = w * 16 + (lane & 15);
        int srow = ((n & 3) << 5) + (n >> 2);
        int k = ((lane >> 4) & 3) * 8 + j;
        p.pWhhS[i] = f2e4m3(p.pWhh[srow * 32 + k]);
      }
      break;
    case 14:
      for (int i = tid0; i < 128; i += stride) {
        int srow = ((i & 3) << 5) + (i >> 2);
        p.pbR[i] = p.pbih[srow] + p.pbhh[srow];
      }
      break;
    case 15: // decode combined weights fp8, swizzled-contiguous stream layout
      for (int i = tid0; i < 262144; i += stride) {
        int j = i & 7, lane = (i >> 3) & 63, kt = (i >> 9) & 7;
        int gate = (i >> 12) & 3, g16 = i >> 14;
        int srow = gate * 256 + g16 * 16 + (lane & 15);
        int k = kt * 32 + ((lane >> 4) & 3) * 8 + j;
        p.WsS[i] = f2e4m3(p.rWih[srow * 256 + k] + p.rWhh[srow * 256 + k]);
      }
      break;
  }
}

// ---------------------------------------------------------------------------
// gemm_act v2: weights in fragment-stream layout (contiguous 1KB per frag).
// ---------------------------------------------------------------------------
__global__ __launch_bounds__(256) void gemm_act(
    const u16* __restrict__ X, const u16* __restrict__ W,
    const float* __restrict__ bias,
    u16* __restrict__ Yb, float* __restrict__ Yf,
    int K, int ldo, int coloff, int leaky) {
  const int rt = blockIdx.x, ct = blockIdx.y;
  const int lane = threadIdx.x & 63, wave = threadIdx.x >> 6;
  const int m15 = lane & 15, q = lane >> 4, kq = q * 8;
  const int KT = K >> 5;
  const int row = rt * 64 + wave * 16 + m15;
  f32x4 acc[4] = {};
  const u16* xp = X + (size_t)row * K + kq;
  const u16* wst = W + lane * 8;
  for (int kt = 0; kt < KT; kt++) {
    bfrag a = *(const bfrag*)(xp + kt * 32);
#pragma unroll
    for (int nt = 0; nt < 4; nt++) {
      const u16* wp = wst + (size_t)((ct * 4 + nt) * KT + kt) * 512;
      acc[nt] = MFMA(a, *(const bfrag*)wp, acc[nt]);
    }
  }
#pragma unroll
  for (int nt = 0; nt < 4; nt++) {
    int col = ct * 64 + nt * 16 + m15;
    float bv = bias[col];
#pragma unroll
    for (int r = 0; r < 4; r++) {
      int orow = rt * 64 + wave * 16 + q * 4 + r;
      float v = acc[nt][r] + bv;
      if (leaky) v = v >= 0.f ? v : 0.2f * v;
      if (Yb) Yb[(size_t)orow * ldo + coloff + col] = f2b(v);
      else    Yf[(size_t)orow * ldo + coloff + col] = v;
    }
  }
}

// ---------------------------------------------------------------------------
// decode_step: step 0 only (K=512 concat input, bf16), gate-retiled columns.
// ---------------------------------------------------------------------------
__global__ __launch_bounds__(256) void decode_step(
    const u16* __restrict__ A, const u16* __restrict__ W,
    const float* __restrict__ rb,
    float* __restrict__ C, u16* __restrict__ Hout, int K) {
  __shared__ float g[64][128];
  const int rt = blockIdx.x, cg = blockIdx.y;
  const int lane = threadIdx.x & 63, wave = threadIdx.x >> 6;
  const int m15 = lane & 15, q = lane >> 4, kq = q * 8;
  const int row = rt * 64 + wave * 16 + m15;
  f32x4 acc[8] = {};
  const u16* ap = A + (size_t)row * K + kq;
  for (int k0 = 0; k0 < K; k0 += 32) {
    bfrag a = *(const bfrag*)(ap + k0);
#pragma unroll
    for (int nt = 0; nt < 8; nt++) {
      const u16* wp = W + (size_t)(cg * 128 + nt * 16 + m15) * K + k0 + kq;
      acc[nt] = MFMA(a, *(const bfrag*)wp, acc[nt]);
    }
  }
#pragma unroll
  for (int nt = 0; nt < 8; nt++)
#pragma unroll
    for (int r = 0; r < 4; r++)
      g[wave * 16 + q * 4 + r][nt * 16 + m15] = acc[nt][r];
  __syncthreads();
  for (int t = threadIdx.x; t < 2048; t += 256) {
    int rl = t >> 5, hc = t & 31;
    int grow = rt * 64 + rl, gcol = cg * 32 + hc;
    int base = ((hc >> 4) << 6) + (hc & 15);
    float gi = g[rl][base +  0] + rb[cg * 128 + base +  0];
    float gf = g[rl][base + 16] + rb[cg * 128 + base + 16];
    float gg = g[rl][base + 32] + rb[cg * 128 + base + 32];
    float go = g[rl][base + 48] + rb[cg * 128 + base + 48];
    size_t ci = (size_t)grow * 256 + gcol;
    float c = C[ci];
    float2 hc2 = lstm2(gi, gf, gg, go, c);
    C[ci] = hc2.y;
    Hout[ci] = f2b(hc2.x);
  }
}

// ---------------------------------------------------------------------------
// decode_h v12: h exchange in STREAM layout (conflict-free LDS), bias as
// MFMA C-init from pinned VGPRs, gate-o weights in LDS (stream, conflict-
// free), gates i/f/g AGPR-pinned, shared-denominator rcp LSTM.
// Stream layout bijection (verified): lane (w,m15,q) writes its packed b32
// (4 hcols w*16+q*4..+3) at (w>>1)*512 + ((w&1)*2+(q>>1))*128 + m15*8 +
// (q&1)*4; fragment read kt is lds[kt*512 + lane*8] (stride-1, 2-way = free).
// hG carries the same 4096B stream image so pred's stage copy is linear.
// ---------------------------------------------------------------------------
__global__ __attribute__((amdgpu_flat_work_group_size(1024, 1024), amdgpu_waves_per_eu(4, 4)))
void decode_h(
    const u8* __restrict__ WsS,     // [262144] swizzled fp8 decode weights
    const float* __restrict__ rb,   // rbR [1024]
    const float* __restrict__ C0,   // CB  [1024][256] (c after step 0)
    const u16* __restrict__ H0,     // h_0 [1024][256] bf16
    u8* __restrict__ hG) {          // [64][128][4096] fp8 h stream (stream lay)
  __shared__ __align__(16) u8 hbufS[2][4096];   // 8 KB h ping-pong (stream)
  __shared__ __align__(16) u8 WoL[16][4096];    // 64 KB gate-o weights
  const int tid = threadIdx.x;
  const int w = tid >> 6, lane = tid & 63;
  const int m15 = lane & 15, q = lane >> 4;
  const int b = blockIdx.x;
  const int rowg = b * 16;

  // stage gate-o weights (stream slices) into LDS once
  {
    int4* dst = (int4*)WoL;
    for (int i = tid; i < 4096; i += 1024) {
      int wv = i >> 8, rest = i & 255;
      dst[i] = ((const int4*)(WsS + wv * 16384 + 12288))[rest];
    }
  }
  // h_0 -> fp8 into hbufS[0] (stream) and hG[b][0]
  {
    int r = tid >> 6, c = (tid & 63) * 4;
    const u16* src = H0 + (size_t)(rowg + r) * 256 + c;
    float f0, f1, f2, f3;
    { union { float f; unsigned u; } v; v.u = (unsigned)src[0] << 16; f0 = v.f; }
    { union { float f; unsigned u; } v; v.u = (unsigned)src[1] << 16; f1 = v.f; }
    { union { float f; unsigned u; } v; v.u = (unsigned)src[2] << 16; f2 = v.f; }
    { union { float f; unsigned u; } v; v.u = (unsigned)src[3] << 16; f3 = v.f; }
    unsigned hv = pk4_e4m3(f0, f1, f2, f3);
    int off = (c >> 5) * 512 + ((c >> 3) & 3) * 128 + r * 8 + (c & 4);
    *(unsigned*)(&hbufS[0][off]) = hv;
    *(unsigned*)(hG + (size_t)b * 524288 + off) = hv;
  }
  // c state: (batch m15, hcols w*16+q*4..+3)
  f32x4 cst = *(const f32x4*)(C0 + (size_t)(rowg + m15) * 256 + w * 16 + q * 4);
  // biases: 16 pinned VGPRs, used as MFMA C-init (no per-step LDS reads)
  const float* rbp = rb + w * 64 + q * 4;
  f32x4 rbv0 = *(const f32x4*)(rbp +  0);
  f32x4 rbv1 = *(const f32x4*)(rbp + 16);
  f32x4 rbv2 = *(const f32x4*)(rbp + 32);
  f32x4 rbv3 = *(const f32x4*)(rbp + 48);
  asm volatile("" : "+v"(rbv0), "+v"(rbv1), "+v"(rbv2), "+v"(rbv3));
  // gates i/f/g resident: 24 frags = 48 AGPRs
  const u8* wsb = WsS + (size_t)w * 16384 + lane * 8;
  f8frag Wv0[8], Wv1[8], Wv2[8];
#pragma unroll
  for (int kt = 0; kt < 8; kt++) {
    Wv0[kt] = *(const f8frag*)(wsb + kt * 512);
    Wv1[kt] = *(const f8frag*)(wsb + 4096 + kt * 512);
    Wv2[kt] = *(const f8frag*)(wsb + 8192 + kt * 512);
  }
  PIN_A8(Wv0); PIN_A8(Wv1); PIN_A8(Wv2);
  // per-lane loop-invariant offsets
  const int wroff = (w >> 1) * 512 + ((w & 1) * 2 + (q >> 1)) * 128 + m15 * 8 + (q & 1) * 4;
  const u8* woW = &WoL[w][lane * 8];
  u8* hGs = hG + (size_t)b * 524288 + wroff;
  __syncthreads();

  for (int s = 1; s < 128; s++) {
    PIN_A8(Wv0); PIN_A8(Wv1); PIN_A8(Wv2);
    asm volatile("" : "+v"(rbv0), "+v"(rbv1), "+v"(rbv2), "+v"(rbv3));
    const u8* h8 = &hbufS[(s - 1) & 1][lane * 8];
    f32x4 ai = rbv0, af_ = rbv1, ag = rbv2, ao = rbv3;
#pragma unroll
    for (int kt = 0; kt < 8; kt++) {
      f8frag a8 = *(const f8frag*)(h8 + kt * 512);
      f8frag wo = *(const f8frag*)(woW + kt * 512);
      ai  = MFMA8(Wv0[kt], a8, ai);
      af_ = MFMA8(Wv1[kt], a8, af_);
      ag  = MFMA8(Wv2[kt], a8, ag);
      ao  = MFMA8(wo, a8, ao);
    }
    float hn[4];
#pragma unroll
    for (int r = 0; r < 4; r++) {
      float2 hc2 = lstm2(ai[r], af_[r], ag[r], ao[r], cst[r]);
      hn[r] = hc2.x;
      cst[r] = hc2.y;
    }
    unsigned hv = pk4_e4m3(hn[0], hn[1], hn[2], hn[3]);
    *(unsigned*)(&hbufS[s & 1][wroff]) = hv;
    *(unsigned*)(hGs + s * 4096) = hv;
    LDS_BARRIER();   // hG store-acks float freely across steps
  }
}

// ---- pred_y v2: linear chunk stage, stream frag reads, fused softmax ----
__global__ __launch_bounds__(512, 2) void pred_y(
    const u8* __restrict__ hG,      // [64][128][4096] stream layout
    const u8* __restrict__ pWsS,    // [32768] swizzled fp8 pred x-weights
    const u8* __restrict__ pWhhS,   // [4096] swizzled fp8 pred h-weights
    const float* __restrict__ pb,   // pbR [128]
    float* __restrict__ out) {      // [1024][128][32] final output
  __shared__ __align__(16) u8 stageL[16384];      // 16 KB = 4 steps of h
  __shared__ __align__(16) u8 hp8[2][16][40];
  __shared__ float ysC[4][16][36];
  const int tid = threadIdx.x;      // 0..511
  const int w = tid >> 6, lane = tid & 63;
  const int m15 = lane & 15, q = lane >> 4;
  const int b = blockIdx.x, rowg = b * 16;
  for (int i = tid; i < 2 * 16 * 40; i += 512) (&hp8[0][0][0])[i] = 0;
  // pred weights resident (18 VGPRs)
  const u8* pwsb = pWsS + (size_t)w * 4096 + lane * 8;
  f8frag pbv[8];
#pragma unroll
  for (int kt = 0; kt < 8; kt++) pbv[kt] = *(const f8frag*)(pwsb + kt * 512);
  f8frag phw = *(const f8frag*)(pWhhS + (size_t)w * 512 + lane * 8);
  PIN_V8(pbv);
  asm volatile("" : "+v"(phw));
  const f32x4 pbias = *(const f32x4*)(pb + w * 16 + q * 4);
  float cp = 0.f;
  const int4* hGb = (const int4*)(hG + (size_t)b * 524288);
  // fused-softmax task mapping: task t=tid>>3 -> (si=t>>4, r=t&15), sub=tid&7
  const int t_si = (tid >> 3) >> 4, t_r = (tid >> 3) & 15, sub = tid & 7;
  __syncthreads();

  for (int cs = 0; cs < 32; cs++) {
    // linear copy of 4 h-steps (16 KB) into LDS
    {
      int4* sdst = (int4*)stageL;
      sdst[tid] = hGb[cs * 1024 + tid];
      sdst[tid + 512] = hGb[cs * 1024 + tid + 512];
    }
    __syncthreads();   // waits the vmcnt-dependent LDS writes + all waves
#pragma unroll
    for (int si = 0; si < 4; si++) {
      const int s = cs * 4 + si;
      const u8* xr8 = &stageL[si * 4096 + lane * 8];
      f32x4 pacc = pbias;
#pragma unroll
      for (int kt = 0; kt < 8; kt++) {
        f8frag pav = *(const f8frag*)(xr8 + kt * 512);
        pacc = MFMA8(pbv[kt], pav, pacc);
      }
      f8frag pah = *(const f8frag*)(&hp8[s & 1][m15][q * 8]);
      pacc = MFMA8(phw, pah, pacc);
      // lane (m15,q) holds gates i,f,g,o of (batch m15, predcol w*4+q)
      float2 hc2 = lstm2(pacc[0], pacc[1], pacc[2], pacc[3], cp);
      cp = hc2.y;
      hp8[(s + 1) & 1][m15][w * 4 + q] = f2e4m3(hc2.x);
      ysC[si][m15][w * 4 + q] = hc2.x;
      LDS_BARRIER();
    }
    // fused softmax + sigmoid + final store for this chunk (4 steps)
    {
      f32x4 yv = *(const f32x4*)&ysC[t_si][t_r][sub * 4];
      float v3 = (sub == 7) ? -1e30f : yv[3];
      float m = fmaxf(fmaxf(yv[0], yv[1]), fmaxf(yv[2], v3));
#pragma unroll
      for (int off = 4; off; off >>= 1) m = fmaxf(m, __shfl_xor(m, off, 8));
      float e0 = __expf(yv[0] - m), e1 = __expf(yv[1] - m), e2 = __expf(yv[2] - m);
      float e3 = (sub == 7) ? 0.f : __expf(yv[3] - m);
      float tot = e0 + e1 + e2 + e3;
#pragma unroll
      for (int off = 4; off; off >>= 1) tot += __shfl_xor(tot, off, 8);
      float inv = rcp(tot);
      f32x4 o;
      o[0] = e0 * inv; o[1] = e1 * inv; o[2] = e2 * inv;
      o[3] = (sub == 7) ? ssig(yv[3]) : e3 * inv;
      *(f32x4*)(out + (size_t)(rowg + t_r) * 4096 + (cs * 4 + t_si) * 32 + sub * 4) = o;
    }
    LDS_BARRIER();   // ysC/stage consumed before next chunk overwrites
  }
}

// ---------------------------------------------------------------------------
extern "C" void kernel_launch(void* const* d_in, const int* in_sizes, int n_in,
                              void* d_out, int out_size, void* d_ws, size_t ws_size,
                              hipStream_t stream) {
  (void)in_sizes; (void)n_in; (void)out_size; (void)ws_size;
  const float* x    = (const float*)d_in[0];
  const float* W1   = (const float*)d_in[1];
  const float* b1   = (const float*)d_in[2];
  const float* W2   = (const float*)d_in[3];
  const float* b2   = (const float*)d_in[4];
  const float* W3   = (const float*)d_in[5];
  const float* b3   = (const float*)d_in[6];
  const float* Wh1  = (const float*)d_in[7];
  const float* bh1  = (const float*)d_in[8];
  const float* Wh2  = (const float*)d_in[9];
  const float* bh2  = (const float*)d_in[10];
  const float* Wc1  = (const float*)d_in[11];
  const float* bc1  = (const float*)d_in[12];
  const float* Wc2  = (const float*)d_in[13];
  const float* bc2  = (const float*)d_in[14];
  const float* Wx1  = (const float*)d_in[15];
  const float* bx1  = (const float*)d_in[16];
  const float* Wx2  = (const float*)d_in[17];
  const float* bx2  = (const float*)d_in[18];
  const float* rWih = (const float*)d_in[19];
  const float* rWhh = (const float*)d_in[20];
  const float* rbih = (const float*)d_in[21];
  const float* rbhh = (const float*)d_in[22];
  const float* pWih = (const float*)d_in[23];
  const float* pWhh = (const float*)d_in[24];
  const float* pbih = (const float*)d_in[25];
  const float* pbhh = (const float*)d_in[26];

  char* w = (char*)d_ws;
  auto alloc = [&](size_t bytes) -> char* {
    char* p = w;
    w += (bytes + 255) & ~(size_t)255;
    return p;
  };
  u16* Xbf  = (u16*)alloc(1024 * 128 * 2);
  u16* T1   = (u16*)alloc(1024 * 512 * 2);
  u16* T2   = (u16*)alloc(1024 * 512 * 2);
  u16* T3   = (u16*)alloc(1024 * 512 * 2);
  u16* TH   = (u16*)alloc(1024 * 512 * 2);
  u16* TC   = (u16*)alloc(1024 * 512 * 2);
  u16* TX   = (u16*)alloc(1024 * 512 * 2);
  u16* X0H  = (u16*)alloc(1024 * 512 * 2);  // cols 0..255 = x0, 256..511 = h
  float* CB = (float*)alloc(1024 * 256 * 4);
  u16* OUTS0= (u16*)alloc(1024 * 256 * 2);  // h_0 only
  u16* W1b  = (u16*)alloc(512 * 128 * 2);
  u16* W2b  = (u16*)alloc(512 * 512 * 2);
  u16* W3b  = (u16*)alloc(512 * 512 * 2);
  u16* Wh1b = (u16*)alloc(512 * 512 * 2);
  u16* Wc1b = (u16*)alloc(512 * 512 * 2);
  u16* Wx1b = (u16*)alloc(512 * 512 * 2);
  u16* Wh2b = (u16*)alloc(256 * 512 * 2);
  u16* Wc2b = (u16*)alloc(256 * 512 * 2);
  u16* Wx2b = (u16*)alloc(256 * 512 * 2);
  u16* WcatR= (u16*)alloc(1024 * 512 * 2);
  u8*  WsS  = (u8*)alloc(262144);
  u8*  pWsS = (u8*)alloc(32768);
  u8*  pWhhS= (u8*)alloc(4096);
  float* rbR = (float*)alloc(1024 * 4);
  float* pbR = (float*)alloc(128 * 4);
  u8*  hG   = (u8*)alloc((size_t)64 * 128 * 4096);   // 32 MB fp8 h stream

  PrepArgs pa;
  pa.x = x; pa.W1 = W1; pa.W2 = W2; pa.W3 = W3; pa.Wh1 = Wh1; pa.Wc1 = Wc1; pa.Wx1 = Wx1;
  pa.Wh2 = Wh2; pa.Wc2 = Wc2; pa.Wx2 = Wx2;
  pa.rWih = rWih; pa.rWhh = rWhh; pa.rbih = rbih; pa.rbhh = rbhh;
  pa.pWih = pWih; pa.pWhh = pWhh; pa.pbih = pbih; pa.pbhh = pbhh;
  pa.Xbf = Xbf; pa.W1b = W1b; pa.W2b = W2b; pa.W3b = W3b; pa.Wh1b = Wh1b;
  pa.Wc1b = Wc1b; pa.Wx1b = Wx1b; pa.Wh2b = Wh2b; pa.Wc2b = Wc2b; pa.Wx2b = Wx2b;
  pa.WcatR = WcatR;
  pa.WsS = WsS; pa.pWsS = pWsS; pa.pWhhS = pWhhS;
  pa.rbR = rbR; pa.pbR = pbR;
  prep<<<dim3(32, 16), 256, 0, stream>>>(pa);

  // MLP + heads (stream-layout weights)
  gemm_act<<<dim3(16, 8), 256, 0, stream>>>(Xbf, W1b, b1, T1, nullptr, 128, 512, 0, 1);
  gemm_act<<<dim3(16, 8), 256, 0, stream>>>(T1, W2b, b2, T2, nullptr, 512, 512, 0, 1);
  gemm_act<<<dim3(16, 8), 256, 0, stream>>>(T2, W3b, b3, T3, nullptr, 512, 512, 0, 1);
  gemm_act<<<dim3(16, 8), 256, 0, stream>>>(T3, Wh1b, bh1, TH, nullptr, 512, 512, 0, 1);
  gemm_act<<<dim3(16, 8), 256, 0, stream>>>(T3, Wc1b, bc1, TC, nullptr, 512, 512, 0, 1);
  gemm_act<<<dim3(16, 8), 256, 0, stream>>>(T3, Wx1b, bx1, TX, nullptr, 512, 512, 0, 1);
  gemm_act<<<dim3(16, 4), 256, 0, stream>>>(TH, Wh2b, bh2, X0H, nullptr, 512, 512, 256, 0); // h
  gemm_act<<<dim3(16, 4), 256, 0, stream>>>(TC, Wc2b, bc2, nullptr, CB, 512, 256, 0, 0);    // c (fp32)
  gemm_act<<<dim3(16, 4), 256, 0, stream>>>(TX, Wx2b, bx2, X0H, nullptr, 512, 512, 0, 0);   // x0

  // decode step 0, then stream-ordered decode -> pred(+fused softmax)
  decode_step<<<dim3(16, 8), 256, 0, stream>>>(X0H, WcatR, rbR, CB, OUTS0, 512);
  decode_h<<<64, 1024, 0, stream>>>(WsS, rbR, CB, OUTS0, hG);
  pred_y<<<64, 512, 0, stream>>>(hG, pWsS, pWhhS, pbR, (float*)d_out);
}

// Round 9
// 516.907 us; speedup vs baseline: 1.5662x; 1.0035x over previous
//
#include <hip/hip_runtime.h>
#include <hip/hip_fp8.h>

typedef unsigned short u16;
typedef unsigned char u8;
typedef __attribute__((ext_vector_type(8))) __bf16 bfrag;
typedef long long f8frag;
typedef __attribute__((ext_vector_type(4))) float f32x4;

static __device__ __forceinline__ f32x4 MFMA(bfrag a, bfrag b, f32x4 c) {
  return __builtin_amdgcn_mfma_f32_16x16x32_bf16(a, b, c, 0, 0, 0);
}
static __device__ __forceinline__ f32x4 MFMA8(f8frag a, f8frag b, f32x4 c) {
  return __builtin_amdgcn_mfma_f32_16x16x32_fp8_fp8(a, b, c, 0, 0, 0);
}

// float -> bf16 (RNE)
static __device__ __forceinline__ u16 f2b(float f) {
  union { float f; unsigned u; } v; v.f = f;
  unsigned r = (v.u + 0x7fffu + ((v.u >> 16) & 1u)) >> 16;
  return (u16)r;
}
// float -> fp8 e4m3 via HW cvt (gfx950: OCP e4m3fn)
static __device__ __forceinline__ u8 f2e4m3(float f) {
  return (u8)(__builtin_amdgcn_cvt_pk_fp8_f32(f, f, 0, false) & 0xff);
}
static __device__ __forceinline__ unsigned pk4_e4m3(float a, float b, float c, float d) {
  int p = __builtin_amdgcn_cvt_pk_fp8_f32(a, b, 0, false);
  p = __builtin_amdgcn_cvt_pk_fp8_f32(c, d, p, true);
  return (unsigned)p;
}
// R5 finding: 1.f/x without fast-math emits the full IEEE div sequence
// (~8 ops). v_rcp_f32 is 1 instr, ~1e-5 rel err << fp8 noise.
static __device__ __forceinline__ float rcp(float x) { return __builtin_amdgcn_rcpf(x); }
static __device__ __forceinline__ float ssig(float x) {
  float E = __expf(x);
  return E * rcp(1.f + E);
}
static __device__ __forceinline__ float stanh(float x) {
  float E = __expf(2.f * x);
  return 1.f - 2.f * rcp(E + 1.f);
}
// Shared-denominator LSTM cell: cn = sig(f)c + sig(i)tanh(g), hn = sig(o)tanh(cn)
// = [c*Ef*QR + Ei*P*(Eg-1)] / (P*QR), Eo(Ec-1)/[(1+Eo)(Ec+1)].
// 7 trans (5 exp + 2 rcp) per value vs 10 trans + 5 IEEE divs before.
static __device__ __forceinline__ float2 lstm2(float gi, float gf, float gg,
                                               float go, float c) {
  float Ei = __expf(gi), Ef = __expf(gf), Eg = __expf(2.f * gg), Eo = __expf(go);
  float P = 1.f + Ef, Q = 1.f + Ei, R = 1.f + Eg;
  float QR = Q * R;
  float num = c * Ef * QR + Ei * P * (Eg - 1.f);
  float cn = num * rcp(P * QR);
  float Ec = __expf(2.f * cn);
  float hn = Eo * (Ec - 1.f) * rcp((1.f + Eo) * (Ec + 1.f));
  return make_float2(hn, cn);
}

// barrier that waits only on LDS traffic (no vmcnt store-ack drain)
#define LDS_BARRIER() asm volatile("s_waitcnt lgkmcnt(0)\ns_barrier" ::: "memory")
#define PIN_A8(A) asm volatile("" : "+a"(A[0]), "+a"(A[1]), "+a"(A[2]), "+a"(A[3]), \
                                    "+a"(A[4]), "+a"(A[5]), "+a"(A[6]), "+a"(A[7]))
#define PIN_V8(A) asm volatile("" : "+v"(A[0]), "+v"(A[1]), "+v"(A[2]), "+v"(A[3]), \
                                    "+v"(A[4]), "+v"(A[5]), "+v"(A[6]), "+v"(A[7]))

// ---------------------------------------------------------------------------
// prep. GEMM weights (cases 1-9) emitted in FRAGMENT-STREAM layout:
//   Wst[(((ct*4+nt)*KT + kt)*64 + lane)*8 + j] = W[ct*64+nt*16+(lane&15)]
//                                                 [kt*32+((lane>>4)&3)*8+j]
// so a wave's (ct,nt,kt) fragment load is one contiguous 1KB block.
// Case 15 (decode) / 12,13 (pred) keep the fp8 stream layout.
// ---------------------------------------------------------------------------
struct PrepArgs {
  const float *x, *W1, *W2, *W3, *Wh1, *Wc1, *Wx1, *Wh2, *Wc2, *Wx2;
  const float *rWih, *rWhh, *rbih, *rbhh, *pWih, *pWhh, *pbih, *pbhh;
  u16 *Xbf, *W1b, *W2b, *W3b, *Wh1b, *Wc1b, *Wx1b, *Wh2b, *Wc2b, *Wx2b;
  u16 *WcatR;
  u8 *WsS, *pWsS, *pWhhS;
  float *rbR, *pbR;
};

// stream emit helper: KT = K/32
static __device__ __forceinline__ void emit_stream(u16* dst, const float* src,
                                                   int i, int K, int ktbits) {
  int j = i & 7, lane = (i >> 3) & 63;
  int kt = (i >> 9) & ((1 << ktbits) - 1);
  int nt = (i >> (9 + ktbits)) & 3;
  int ct = i >> (11 + ktbits);
  int srow = ct * 64 + nt * 16 + (lane & 15);
  int scol = kt * 32 + ((lane >> 4) & 3) * 8 + j;
  dst[i] = f2b(src[srow * K + scol]);
}

__global__ __launch_bounds__(256) void prep(PrepArgs p) {
  const int tid0 = blockIdx.x * 256 + threadIdx.x;
  const int stride = gridDim.x * 256;
  switch (blockIdx.y) {
    case 0: for (int i = tid0; i < 131072; i += stride) p.Xbf[i] = f2b(p.x[i]); break;
    case 1: for (int i = tid0; i < 65536;  i += stride) emit_stream(p.W1b, p.W1, i, 128, 2); break;
    case 2: for (int i = tid0; i < 262144; i += stride) emit_stream(p.W2b, p.W2, i, 512, 4); break;
    case 3: for (int i = tid0; i < 262144; i += stride) emit_stream(p.W3b, p.W3, i, 512, 4); break;
    case 4: for (int i = tid0; i < 262144; i += stride) emit_stream(p.Wh1b, p.Wh1, i, 512, 4); break;
    case 5: for (int i = tid0; i < 262144; i += stride) emit_stream(p.Wc1b, p.Wc1, i, 512, 4); break;
    case 6: for (int i = tid0; i < 262144; i += stride) emit_stream(p.Wx1b, p.Wx1, i, 512, 4); break;
    case 7: for (int i = tid0; i < 131072; i += stride) emit_stream(p.Wh2b, p.Wh2, i, 512, 4); break;
    case 8: for (int i = tid0; i < 131072; i += stride) emit_stream(p.Wc2b, p.Wc2, i, 512, 4); break;
    case 9: for (int i = tid0; i < 131072; i += stride) emit_stream(p.Wx2b, p.Wx2, i, 512, 4); break;
    case 10: // step-0 concat weights (bf16, gate-retiled, row-major: decode_step only)
      for (int i = tid0; i < 262144; i += stride) {
        int n = i >> 8, k = i & 255;
        int srow = (((n >> 4) & 3) << 8) + ((n >> 6) << 4) + (n & 15);
        p.WcatR[n * 512 + k] = f2b(p.rWih[srow * 256 + k]);
        p.WcatR[n * 512 + 256 + k] = f2b(p.rWhh[srow * 256 + k]);
      }
      break;
    case 11:
      for (int i = tid0; i < 1024; i += stride) {
        int srow = (((i >> 4) & 3) << 8) + ((i >> 6) << 4) + (i & 15);
        p.rbR[i] = p.rbih[srow] + p.rbhh[srow];
      }
      break;
    case 12: // pred x-weights fp8, swizzled-contiguous
      for (int i = tid0; i < 32768; i += stride) {
        int j = i & 7, lane = (i >> 3) & 63, kt = (i >> 9) & 7, w = i >> 12;
        int n = w * 16 + (lane & 15);
        int srow = ((n & 3) << 5) + (n >> 2);
        int k = kt * 32 + ((lane >> 4) & 3) * 8 + j;
        p.pWsS[i] = f2e4m3(p.pWih[srow * 256 + k]);
      }
      break;
    case 13: // pred h-weights fp8, swizzled-contiguous
      for (int i = tid0; i < 4096; i += stride) {
        int j = i & 7, lane = (i >> 3) & 63, w = i >> 9;
        int n = w * 16 + (lane & 15);
        int srow = ((n & 3) << 5) + (n >> 2);
        int k = ((lane >> 4) & 3) * 8 + j;
        p.pWhhS[i] = f2e4m3(p.pWhh[srow * 32 + k]);
      }
      break;
    case 14:
      for (int i = tid0; i < 128; i += stride) {
        int srow = ((i & 3) << 5) + (i >> 2);
        p.pbR[i] = p.pbih[srow] + p.pbhh[srow];
      }
      break;
    case 15: // decode combined weights fp8, swizzled-contiguous stream layout
      for (int i = tid0; i < 262144; i += stride) {
        int j = i & 7, lane = (i >> 3) & 63, kt = (i >> 9) & 7;
        int gate = (i >> 12) & 3, g16 = i >> 14;
        int srow = gate * 256 + g16 * 16 + (lane & 15);
        int k = kt * 32 + ((lane >> 4) & 3) * 8 + j;
        p.WsS[i] = f2e4m3(p.rWih[srow * 256 + k] + p.rWhh[srow * 256 + k]);
      }
      break;
  }
}

// ---------------------------------------------------------------------------
// gemm_act v2: weights in fragment-stream layout (contiguous 1KB per frag).
// ---------------------------------------------------------------------------
__global__ __launch_bounds__(256) void gemm_act(
    const u16* __restrict__ X, const u16* __restrict__ W,
    const float* __restrict__ bias,
    u16* __restrict__ Yb, float* __restrict__ Yf,
    int K, int ldo, int coloff, int leaky) {
  const int rt = blockIdx.x, ct = blockIdx.y;
  const int lane = threadIdx.x & 63, wave = threadIdx.x >> 6;
  const int m15 = lane & 15, q = lane >> 4, kq = q * 8;
  const int KT = K >> 5;
  const int row = rt * 64 + wave * 16 + m15;
  f32x4 acc[4] = {};
  const u16* xp = X + (size_t)row * K + kq;
  const u16* wst = W + lane * 8;
  for (int kt = 0; kt < KT; kt++) {
    bfrag a = *(const bfrag*)(xp + kt * 32);
#pragma unroll
    for (int nt = 0; nt < 4; nt++) {
      const u16* wp = wst + (size_t)((ct * 4 + nt) * KT + kt) * 512;
      acc[nt] = MFMA(a, *(const bfrag*)wp, acc[nt]);
    }
  }
#pragma unroll
  for (int nt = 0; nt < 4; nt++) {
    int col = ct * 64 + nt * 16 + m15;
    float bv = bias[col];
#pragma unroll
    for (int r = 0; r < 4; r++) {
      int orow = rt * 64 + wave * 16 + q * 4 + r;
      float v = acc[nt][r] + bv;
      if (leaky) v = v >= 0.f ? v : 0.2f * v;
      if (Yb) Yb[(size_t)orow * ldo + coloff + col] = f2b(v);
      else    Yf[(size_t)orow * ldo + coloff + col] = v;
    }
  }
}

// ---------------------------------------------------------------------------
// decode_step: step 0 only (K=512 concat input, bf16), gate-retiled columns.
// ---------------------------------------------------------------------------
__global__ __launch_bounds__(256) void decode_step(
    const u16* __restrict__ A, const u16* __restrict__ W,
    const float* __restrict__ rb,
    float* __restrict__ C, u16* __restrict__ Hout, int K) {
  __shared__ float g[64][128];
  const int rt = blockIdx.x, cg = blockIdx.y;
  const int lane = threadIdx.x & 63, wave = threadIdx.x >> 6;
  const int m15 = lane & 15, q = lane >> 4, kq = q * 8;
  const int row = rt * 64 + wave * 16 + m15;
  f32x4 acc[8] = {};
  const u16* ap = A + (size_t)row * K + kq;
  for (int k0 = 0; k0 < K; k0 += 32) {
    bfrag a = *(const bfrag*)(ap + k0);
#pragma unroll
    for (int nt = 0; nt < 8; nt++) {
      const u16* wp = W + (size_t)(cg * 128 + nt * 16 + m15) * K + k0 + kq;
      acc[nt] = MFMA(a, *(const bfrag*)wp, acc[nt]);
    }
  }
#pragma unroll
  for (int nt = 0; nt < 8; nt++)
#pragma unroll
    for (int r = 0; r < 4; r++)
      g[wave * 16 + q * 4 + r][nt * 16 + m15] = acc[nt][r];
  __syncthreads();
  for (int t = threadIdx.x; t < 2048; t += 256) {
    int rl = t >> 5, hc = t & 31;
    int grow = rt * 64 + rl, gcol = cg * 32 + hc;
    int base = ((hc >> 4) << 6) + (hc & 15);
    float gi = g[rl][base +  0] + rb[cg * 128 + base +  0];
    float gf = g[rl][base + 16] + rb[cg * 128 + base + 16];
    float gg = g[rl][base + 32] + rb[cg * 128 + base + 32];
    float go = g[rl][base + 48] + rb[cg * 128 + base + 48];
    size_t ci = (size_t)grow * 256 + gcol;
    float c = C[ci];
    float2 hc2 = lstm2(gi, gf, gg, go, c);
    C[ci] = hc2.y;
    Hout[ci] = f2b(hc2.x);
  }
}

// ---------------------------------------------------------------------------
// decode_h v12: h exchange in STREAM layout (conflict-free LDS), bias as
// MFMA C-init from pinned VGPRs, gate-o weights in LDS (stream, conflict-
// free), gates i/f/g AGPR-pinned, shared-denominator rcp LSTM.
// Stream layout bijection (verified): lane (w,m15,q) writes its packed b32
// (4 hcols w*16+q*4..+3) at (w>>1)*512 + ((w&1)*2+(q>>1))*128 + m15*8 +
// (q&1)*4; fragment read kt is lds[kt*512 + lane*8] (stride-1, 2-way = free).
// hG carries the same 4096B stream image so pred's stage copy is linear.
// ---------------------------------------------------------------------------
__global__ __attribute__((amdgpu_flat_work_group_size(1024, 1024), amdgpu_waves_per_eu(4, 4)))
void decode_h(
    const u8* __restrict__ WsS,     // [262144] swizzled fp8 decode weights
    const float* __restrict__ rb,   // rbR [1024]
    const float* __restrict__ C0,   // CB  [1024][256] (c after step 0)
    const u16* __restrict__ H0,     // h_0 [1024][256] bf16
    u8* __restrict__ hG) {          // [64][128][4096] fp8 h stream (stream lay)
  __shared__ __align__(16) u8 hbufS[2][4096];   // 8 KB h ping-pong (stream)
  __shared__ __align__(16) u8 WoL[16][4096];    // 64 KB gate-o weights
  const int tid = threadIdx.x;
  const int w = tid >> 6, lane = tid & 63;
  const int m15 = lane & 15, q = lane >> 4;
  const int b = blockIdx.x;
  const int rowg = b * 16;

  // stage gate-o weights (stream slices) into LDS once
  {
    int4* dst = (int4*)WoL;
    for (int i = tid; i < 4096; i += 1024) {
      int wv = i >> 8, rest = i & 255;
      dst[i] = ((const int4*)(WsS + wv * 16384 + 12288))[rest];
    }
  }
  // h_0 -> fp8 into hbufS[0] (stream) and hG[b][0]
  {
    int r = tid >> 6, c = (tid & 63) * 4;
    const u16* src = H0 + (size_t)(rowg + r) * 256 + c;
    float f0, f1, f2, f3;
    { union { float f; unsigned u; } v; v.u = (unsigned)src[0] << 16; f0 = v.f; }
    { union { float f; unsigned u; } v; v.u = (unsigned)src[1] << 16; f1 = v.f; }
    { union { float f; unsigned u; } v; v.u = (unsigned)src[2] << 16; f2 = v.f; }
    { union { float f; unsigned u; } v; v.u = (unsigned)src[3] << 16; f3 = v.f; }
    unsigned hv = pk4_e4m3(f0, f1, f2, f3);
    int off = (c >> 5) * 512 + ((c >> 3) & 3) * 128 + r * 8 + (c & 4);
    *(unsigned*)(&hbufS[0][off]) = hv;
    *(unsigned*)(hG + (size_t)b * 524288 + off) = hv;
  }
  // c state: (batch m15, hcols w*16+q*4..+3)
  f32x4 cst = *(const f32x4*)(C0 + (size_t)(rowg + m15) * 256 + w * 16 + q * 4);
  // biases: 16 pinned VGPRs, used as MFMA C-init (no per-step LDS reads)
  const float* rbp = rb + w * 64 + q * 4;
  f32x4 rbv0 = *(const f32x4*)(rbp +  0);
  f32x4 rbv1 = *(const f32x4*)(rbp + 16);
  f32x4 rbv2 = *(const f32x4*)(rbp + 32);
  f32x4 rbv3 = *(const f32x4*)(rbp + 48);
  asm volatile("" : "+v"(rbv0), "+v"(rbv1), "+v"(rbv2), "+v"(rbv3));
  // gates i/f/g resident: 24 frags = 48 AGPRs
  const u8* wsb = WsS + (size_t)w * 16384 + lane * 8;
  f8frag Wv0[8], Wv1[8], Wv2[8];
#pragma unroll
  for (int kt = 0; kt < 8; kt++) {
    Wv0[kt] = *(const f8frag*)(wsb + kt * 512);
    Wv1[kt] = *(const f8frag*)(wsb + 4096 + kt * 512);
    Wv2[kt] = *(const f8frag*)(wsb + 8192 + kt * 512);
  }
  PIN_A8(Wv0); PIN_A8(Wv1); PIN_A8(Wv2);
  // per-lane loop-invariant offsets
  const int wroff = (w >> 1) * 512 + ((w & 1) * 2 + (q >> 1)) * 128 + m15 * 8 + (q & 1) * 4;
  const u8* woW = &WoL[w][lane * 8];
  u8* hGs = hG + (size_t)b * 524288 + wroff;
  __syncthreads();

  for (int s = 1; s < 128; s++) {
    PIN_A8(Wv0); PIN_A8(Wv1); PIN_A8(Wv2);
    asm volatile("" : "+v"(rbv0), "+v"(rbv1), "+v"(rbv2), "+v"(rbv3));
    const u8* h8 = &hbufS[(s - 1) & 1][lane * 8];
    f32x4 ai = rbv0, af_ = rbv1, ag = rbv2, ao = rbv3;
#pragma unroll
    for (int kt = 0; kt < 8; kt++) {
      f8frag a8 = *(const f8frag*)(h8 + kt * 512);
      f8frag wo = *(const f8frag*)(woW + kt * 512);
      ai  = MFMA8(Wv0[kt], a8, ai);
      af_ = MFMA8(Wv1[kt], a8, af_);
      ag  = MFMA8(Wv2[kt], a8, ag);
      ao  = MFMA8(wo, a8, ao);
    }
    float hn[4];
#pragma unroll
    for (int r = 0; r < 4; r++) {
      float2 hc2 = lstm2(ai[r], af_[r], ag[r], ao[r], cst[r]);
      hn[r] = hc2.x;
      cst[r] = hc2.y;
    }
    unsigned hv = pk4_e4m3(hn[0], hn[1], hn[2], hn[3]);
    *(unsigned*)(&hbufS[s & 1][wroff]) = hv;
    *(unsigned*)(hGs + s * 4096) = hv;
    LDS_BARRIER();   // hG store-acks float freely across steps
  }
}

// ---- pred_y v2: linear chunk stage, stream frag reads, fused softmax ----
__global__ __launch_bounds__(512, 2) void pred_y(
    const u8* __restrict__ hG,      // [64][128][4096] stream layout
    const u8* __restrict__ pWsS,    // [32768] swizzled fp8 pred x-weights
    const u8* __restrict__ pWhhS,   // [4096] swizzled fp8 pred h-weights
    const float* __restrict__ pb,   // pbR [128]
    float* __restrict__ out) {      // [1024][128][32] final output
  __shared__ __align__(16) u8 stageL[16384];      // 16 KB = 4 steps of h
  __shared__ __align__(16) u8 hp8[2][16][40];
  __shared__ float ysC[4][16][36];
  const int tid = threadIdx.x;      // 0..511
  const int w = tid >> 6, lane = tid & 63;
  const int m15 = lane & 15, q = lane >> 4;
  const int b = blockIdx.x, rowg = b * 16;
  for (int i = tid; i < 2 * 16 * 40; i += 512) (&hp8[0][0][0])[i] = 0;
  // pred weights resident (18 VGPRs)
  const u8* pwsb = pWsS + (size_t)w * 4096 + lane * 8;
  f8frag pbv[8];
#pragma unroll
  for (int kt = 0; kt < 8; kt++) pbv[kt] = *(const f8frag*)(pwsb + kt * 512);
  f8frag phw = *(const f8frag*)(pWhhS + (size_t)w * 512 + lane * 8);
  PIN_V8(pbv);
  asm volatile("" : "+v"(phw));
  const f32x4 pbias = *(const f32x4*)(pb + w * 16 + q * 4);
  float cp = 0.f;
  const int4* hGb = (const int4*)(hG + (size_t)b * 524288);
  // fused-softmax task mapping: task t=tid>>3 -> (si=t>>4, r=t&15), sub=tid&7
  const int t_si = (tid >> 3) >> 4, t_r = (tid >> 3) & 15, sub = tid & 7;
  __syncthreads();

  for (int cs = 0; cs < 32; cs++) {
    // linear copy of 4 h-steps (16 KB) into LDS
    {
      int4* sdst = (int4*)stageL;
      sdst[tid] = hGb[cs * 1024 + tid];
      sdst[tid + 512] = hGb[cs * 1024 + tid + 512];
    }
    __syncthreads();   // waits the vmcnt-dependent LDS writes + all waves
#pragma unroll
    for (int si = 0; si < 4; si++) {
      const int s = cs * 4 + si;
      const u8* xr8 = &stageL[si * 4096 + lane * 8];
      f32x4 pacc = pbias;
#pragma unroll
      for (int kt = 0; kt < 8; kt++) {
        f8frag pav = *(const f8frag*)(xr8 + kt * 512);
        pacc = MFMA8(pbv[kt], pav, pacc);
      }
      f8frag pah = *(const f8frag*)(&hp8[s & 1][m15][q * 8]);
      pacc = MFMA8(phw, pah, pacc);
      // lane (m15,q) holds gates i,f,g,o of (batch m15, predcol w*4+q)
      float2 hc2 = lstm2(pacc[0], pacc[1], pacc[2], pacc[3], cp);
      cp = hc2.y;
      hp8[(s + 1) & 1][m15][w * 4 + q] = f2e4m3(hc2.x);
      ysC[si][m15][w * 4 + q] = hc2.x;
      LDS_BARRIER();
    }
    // fused softmax + sigmoid + final store for this chunk (4 steps)
    {
      f32x4 yv = *(const f32x4*)&ysC[t_si][t_r][sub * 4];
      float v3 = (sub == 7) ? -1e30f : yv[3];
      float m = fmaxf(fmaxf(yv[0], yv[1]), fmaxf(yv[2], v3));
#pragma unroll
      for (int off = 4; off; off >>= 1) m = fmaxf(m, __shfl_xor(m, off, 8));
      float e0 = __expf(yv[0] - m), e1 = __expf(yv[1] - m), e2 = __expf(yv[2] - m);
      float e3 = (sub == 7) ? 0.f : __expf(yv[3] - m);
      float tot = e0 + e1 + e2 + e3;
#pragma unroll
      for (int off = 4; off; off >>= 1) tot += __shfl_xor(tot, off, 8);
      float inv = rcp(tot);
      f32x4 o;
      o[0] = e0 * inv; o[1] = e1 * inv; o[2] = e2 * inv;
      o[3] = (sub == 7) ? ssig(yv[3]) : e3 * inv;
      *(f32x4*)(out + (size_t)(rowg + t_r) * 4096 + (cs * 4 + t_si) * 32 + sub * 4) = o;
    }
    LDS_BARRIER();   // ysC/stage consumed before next chunk overwrites
  }
}

// ---------------------------------------------------------------------------
extern "C" void kernel_launch(void* const* d_in, const int* in_sizes, int n_in,
                              void* d_out, int out_size, void* d_ws, size_t ws_size,
                              hipStream_t stream) {
  (void)in_sizes; (void)n_in; (void)out_size; (void)ws_size;
  const float* x    = (const float*)d_in[0];
  const float* W1   = (const float*)d_in[1];
  const float* b1   = (const float*)d_in[2];
  const float* W2   = (const float*)d_in[3];
  const float* b2   = (const float*)d_in[4];
  const float* W3   = (const float*)d_in[5];
  const float* b3   = (const float*)d_in[6];
  const float* Wh1  = (const float*)d_in[7];
  const float* bh1  = (const float*)d_in[8];
  const float* Wh2  = (const float*)d_in[9];
  const float* bh2  = (const float*)d_in[10];
  const float* Wc1  = (const float*)d_in[11];
  const float* bc1  = (const float*)d_in[12];
  const float* Wc2  = (const float*)d_in[13];
  const float* bc2  = (const float*)d_in[14];
  const float* Wx1  = (const float*)d_in[15];
  const float* bx1  = (const float*)d_in[16];
  const float* Wx2  = (const float*)d_in[17];
  const float* bx2  = (const float*)d_in[18];
  const float* rWih = (const float*)d_in[19];
  const float* rWhh = (const float*)d_in[20];
  const float* rbih = (const float*)d_in[21];
  const float* rbhh = (const float*)d_in[22];
  const float* pWih = (const float*)d_in[23];
  const float* pWhh = (const float*)d_in[24];
  const float* pbih = (const float*)d_in[25];
  const float* pbhh = (const float*)d_in[26];

  char* w = (char*)d_ws;
  auto alloc = [&](size_t bytes) -> char* {
    char* p = w;
    w += (bytes + 255) & ~(size_t)255;
    return p;
  };
  u16* Xbf  = (u16*)alloc(1024 * 128 * 2);
  u16* T1   = (u16*)alloc(1024 * 512 * 2);
  u16* T2   = (u16*)alloc(1024 * 512 * 2);
  u16* T3   = (u16*)alloc(1024 * 512 * 2);
  u16* TH   = (u16*)alloc(1024 * 512 * 2);
  u16* TC   = (u16*)alloc(1024 * 512 * 2);
  u16* TX   = (u16*)alloc(1024 * 512 * 2);
  u16* X0H  = (u16*)alloc(1024 * 512 * 2);  // cols 0..255 = x0, 256..511 = h
  float* CB = (float*)alloc(1024 * 256 * 4);
  u16* OUTS0= (u16*)alloc(1024 * 256 * 2);  // h_0 only
  u16* W1b  = (u16*)alloc(512 * 128 * 2);
  u16* W2b  = (u16*)alloc(512 * 512 * 2);
  u16* W3b  = (u16*)alloc(512 * 512 * 2);
  u16* Wh1b = (u16*)alloc(512 * 512 * 2);
  u16* Wc1b = (u16*)alloc(512 * 512 * 2);
  u16* Wx1b = (u16*)alloc(512 * 512 * 2);
  u16* Wh2b = (u16*)alloc(256 * 512 * 2);
  u16* Wc2b = (u16*)alloc(256 * 512 * 2);
  u16* Wx2b = (u16*)alloc(256 * 512 * 2);
  u16* WcatR= (u16*)alloc(1024 * 512 * 2);
  u8*  WsS  = (u8*)alloc(262144);
  u8*  pWsS = (u8*)alloc(32768);
  u8*  pWhhS= (u8*)alloc(4096);
  float* rbR = (float*)alloc(1024 * 4);
  float* pbR = (float*)alloc(128 * 4);
  u8*  hG   = (u8*)alloc((size_t)64 * 128 * 4096);   // 32 MB fp8 h stream

  PrepArgs pa;
  pa.x = x; pa.W1 = W1; pa.W2 = W2; pa.W3 = W3; pa.Wh1 = Wh1; pa.Wc1 = Wc1; pa.Wx1 = Wx1;
  pa.Wh2 = Wh2; pa.Wc2 = Wc2; pa.Wx2 = Wx2;
  pa.rWih = rWih; pa.rWhh = rWhh; pa.rbih = rbih; pa.rbhh = rbhh;
  pa.pWih = pWih; pa.pWhh = pWhh; pa.pbih = pbih; pa.pbhh = pbhh;
  pa.Xbf = Xbf; pa.W1b = W1b; pa.W2b = W2b; pa.W3b = W3b; pa.Wh1b = Wh1b;
  pa.Wc1b = Wc1b; pa.Wx1b = Wx1b; pa.Wh2b = Wh2b; pa.Wc2b = Wc2b; pa.Wx2b = Wx2b;
  pa.WcatR = WcatR;
  pa.WsS = WsS; pa.pWsS = pWsS; pa.pWhhS = pWhhS;
  pa.rbR = rbR; pa.pbR = pbR;
  prep<<<dim3(32, 16), 256, 0, stream>>>(pa);

  // MLP + heads (stream-layout weights)
  gemm_act<<<dim3(16, 8), 256, 0, stream>>>(Xbf, W1b, b1, T1, nullptr, 128, 512, 0, 1);
  gemm_act<<<dim3(16, 8), 256, 0, stream>>>(T1, W2b, b2, T2, nullptr, 512, 512, 0, 1);
  gemm_act<<<dim3(16, 8), 256, 0, stream>>>(T2, W3b, b3, T3, nullptr, 512, 512, 0, 1);
  gemm_act<<<dim3(16, 8), 256, 0, stream>>>(T3, Wh1b, bh1, TH, nullptr, 512, 512, 0, 1);
  gemm_act<<<dim3(16, 8), 256, 0, stream>>>(T3, Wc1b, bc1, TC, nullptr, 512, 512, 0, 1);
  gemm_act<<<dim3(16, 8), 256, 0, stream>>>(T3, Wx1b, bx1, TX, nullptr, 512, 512, 0, 1);
  gemm_act<<<dim3(16, 4), 256, 0, stream>>>(TH, Wh2b, bh2, X0H, nullptr, 512, 512, 256, 0); // h
  gemm_act<<<dim3(16, 4), 256, 0, stream>>>(TC, Wc2b, bc2, nullptr, CB, 512, 256, 0, 0);    // c (fp32)
  gemm_act<<<dim3(16, 4), 256, 0, stream>>>(TX, Wx2b, bx2, X0H, nullptr, 512, 512, 0, 0);   // x0

  // decode step 0, then stream-ordered decode -> pred(+fused softmax)
  decode_step<<<dim3(16, 8), 256, 0, stream>>>(X0H, WcatR, rbR, CB, OUTS0, 512);
  decode_h<<<64, 1024, 0, stream>>>(WsS, rbR, CB, OUTS0, hG);
  pred_y<<<64, 512, 0, stream>>>(hG, pWsS, pWhhS, pbR, (float*)d_out);
}

// Round 10
// 487.290 us; speedup vs baseline: 1.6614x; 1.0608x over previous
//
#include <hip/hip_runtime.h>
#include <hip/hip_fp8.h>

typedef unsigned short u16;
typedef unsigned char u8;
typedef __attribute__((ext_vector_type(8))) __bf16 bfrag;
typedef long long f8frag;
typedef __attribute__((ext_vector_type(4))) float f32x4;

static __device__ __forceinline__ f32x4 MFMA(bfrag a, bfrag b, f32x4 c) {
  return __builtin_amdgcn_mfma_f32_16x16x32_bf16(a, b, c, 0, 0, 0);
}
static __device__ __forceinline__ f32x4 MFMA8(f8frag a, f8frag b, f32x4 c) {
  return __builtin_amdgcn_mfma_f32_16x16x32_fp8_fp8(a, b, c, 0, 0, 0);
}

// float -> bf16 (RNE)
static __device__ __forceinline__ u16 f2b(float f) {
  union { float f; unsigned u; } v; v.f = f;
  unsigned r = (v.u + 0x7fffu + ((v.u >> 16) & 1u)) >> 16;
  return (u16)r;
}
// float -> fp8 e4m3 via HW cvt (gfx950: OCP e4m3fn)
static __device__ __forceinline__ u8 f2e4m3(float f) {
  return (u8)(__builtin_amdgcn_cvt_pk_fp8_f32(f, f, 0, false) & 0xff);
}
static __device__ __forceinline__ unsigned pk4_e4m3(float a, float b, float c, float d) {
  int p = __builtin_amdgcn_cvt_pk_fp8_f32(a, b, 0, false);
  p = __builtin_amdgcn_cvt_pk_fp8_f32(c, d, p, true);
  return (unsigned)p;
}
// 1.f/x without fast-math emits the IEEE div sequence (~8 ops); v_rcp is 1.
static __device__ __forceinline__ float rcp(float x) { return __builtin_amdgcn_rcpf(x); }
static __device__ __forceinline__ float ssig(float x) {
  float E = __expf(x);
  return E * rcp(1.f + E);
}
// Shared-denominator LSTM cell (harness-verified R6/R9):
// cn = [c*Ef*QR + Ei*P*(Eg-1)] / (P*QR), hn = Eo(Ec-1)/[(1+Eo)(Ec+1)].
static __device__ __forceinline__ float2 lstm2(float gi, float gf, float gg,
                                               float go, float c) {
  float Ei = __expf(gi), Ef = __expf(gf), Eg = __expf(2.f * gg), Eo = __expf(go);
  float P = 1.f + Ef, Q = 1.f + Ei, R = 1.f + Eg;
  float QR = Q * R;
  float num = c * Ef * QR + Ei * P * (Eg - 1.f);
  float cn = num * rcp(P * QR);
  float Ec = __expf(2.f * cn);
  float hn = Eo * (Ec - 1.f) * rcp((1.f + Eo) * (Ec + 1.f));
  return make_float2(hn, cn);
}

// barrier that waits only on LDS traffic (no vmcnt store-ack drain)
#define LDS_BARRIER() asm volatile("s_waitcnt lgkmcnt(0)\ns_barrier" ::: "memory")
#define PIN_A8(A) asm volatile("" : "+a"(A[0]), "+a"(A[1]), "+a"(A[2]), "+a"(A[3]), \
                                    "+a"(A[4]), "+a"(A[5]), "+a"(A[6]), "+a"(A[7]))
#define PIN_V8(A) asm volatile("" : "+v"(A[0]), "+v"(A[1]), "+v"(A[2]), "+v"(A[3]), \
                                    "+v"(A[4]), "+v"(A[5]), "+v"(A[6]), "+v"(A[7]))

// ---------------------------------------------------------------------------
// prep. All GEMM weights in FRAGMENT-STREAM layout (contiguous 1KB/frag).
// Case 10: step-0 concat weights, gate-retiled + stream over K=512 [rWih|rWhh]:
//   WcatR[(((w16*4+gate)*16+kt)*64+lane)*8+j]
//     = bf16( Wsrc[gate*256 + w16*16 + (lane&15)][kt*32+((lane>>4)&3)*8+j] )
//   where col k<256 -> rWih[.][k], k>=256 -> rWhh[.][k-256].
// ---------------------------------------------------------------------------
struct PrepArgs {
  const float *x, *W1, *W2, *W3, *Wh1, *Wc1, *Wx1, *Wh2, *Wc2, *Wx2;
  const float *rWih, *rWhh, *rbih, *rbhh, *pWih, *pWhh, *pbih, *pbhh;
  u16 *Xbf, *W1b, *W2b, *W3b, *Wh1b, *Wc1b, *Wx1b, *Wh2b, *Wc2b, *Wx2b;
  u16 *WcatR;
  u8 *WsS, *pWsS, *pWhhS;
  float *rbR, *pbR;
};

static __device__ __forceinline__ void emit_stream(u16* dst, const float* src,
                                                   int i, int K, int ktbits) {
  int j = i & 7, lane = (i >> 3) & 63;
  int kt = (i >> 9) & ((1 << ktbits) - 1);
  int nt = (i >> (9 + ktbits)) & 3;
  int ct = i >> (11 + ktbits);
  int srow = ct * 64 + nt * 16 + (lane & 15);
  int scol = kt * 32 + ((lane >> 4) & 3) * 8 + j;
  dst[i] = f2b(src[srow * K + scol]);
}

__global__ __launch_bounds__(256) void prep(PrepArgs p) {
  const int tid0 = blockIdx.x * 256 + threadIdx.x;
  const int stride = gridDim.x * 256;
  switch (blockIdx.y) {
    case 0: for (int i = tid0; i < 131072; i += stride) p.Xbf[i] = f2b(p.x[i]); break;
    case 1: for (int i = tid0; i < 65536;  i += stride) emit_stream(p.W1b, p.W1, i, 128, 2); break;
    case 2: for (int i = tid0; i < 262144; i += stride) emit_stream(p.W2b, p.W2, i, 512, 4); break;
    case 3: for (int i = tid0; i < 262144; i += stride) emit_stream(p.W3b, p.W3, i, 512, 4); break;
    case 4: for (int i = tid0; i < 262144; i += stride) emit_stream(p.Wh1b, p.Wh1, i, 512, 4); break;
    case 5: for (int i = tid0; i < 262144; i += stride) emit_stream(p.Wc1b, p.Wc1, i, 512, 4); break;
    case 6: for (int i = tid0; i < 262144; i += stride) emit_stream(p.Wx1b, p.Wx1, i, 512, 4); break;
    case 7: for (int i = tid0; i < 131072; i += stride) emit_stream(p.Wh2b, p.Wh2, i, 512, 4); break;
    case 8: for (int i = tid0; i < 131072; i += stride) emit_stream(p.Wc2b, p.Wc2, i, 512, 4); break;
    case 9: for (int i = tid0; i < 131072; i += stride) emit_stream(p.Wx2b, p.Wx2, i, 512, 4); break;
    case 10: // step-0 concat weights, gate-retiled + stream (K=512)
      for (int i = tid0; i < 524288; i += stride) {
        int j = i & 7, lane = (i >> 3) & 63, kt = (i >> 9) & 15;
        int gate = (i >> 13) & 3, w16 = i >> 15;
        int srow = gate * 256 + w16 * 16 + (lane & 15);
        int k = kt * 32 + ((lane >> 4) & 3) * 8 + j;
        float v = (k < 256) ? p.rWih[srow * 256 + k] : p.rWhh[srow * 256 + (k - 256)];
        p.WcatR[i] = f2b(v);
      }
      break;
    case 11:
      for (int i = tid0; i < 1024; i += stride) {
        int srow = (((i >> 4) & 3) << 8) + ((i >> 6) << 4) + (i & 15);
        p.rbR[i] = p.rbih[srow] + p.rbhh[srow];
      }
      break;
    case 12: // pred x-weights fp8, swizzled-contiguous
      for (int i = tid0; i < 32768; i += stride) {
        int j = i & 7, lane = (i >> 3) & 63, kt = (i >> 9) & 7, w = i >> 12;
        int n = w * 16 + (lane & 15);
        int srow = ((n & 3) << 5) + (n >> 2);
        int k = kt * 32 + ((lane >> 4) & 3) * 8 + j;
        p.pWsS[i] = f2e4m3(p.pWih[srow * 256 + k]);
      }
      break;
    case 13: // pred h-weights fp8, swizzled-contiguous
      for (int i = tid0; i < 4096; i += stride) {
        int j = i & 7, lane = (i >> 3) & 63, w = i >> 9;
        int n = w * 16 + (lane & 15);
        int srow = ((n & 3) << 5) + (n >> 2);
        int k = ((lane >> 4) & 3) * 8 + j;
        p.pWhhS[i] = f2e4m3(p.pWhh[srow * 32 + k]);
      }
      break;
    case 14:
      for (int i = tid0; i < 128; i += stride) {
        int srow = ((i & 3) << 5) + (i >> 2);
        p.pbR[i] = p.pbih[srow] + p.pbhh[srow];
      }
      break;
    case 15: // decode combined weights fp8, swizzled-contiguous stream layout
      for (int i = tid0; i < 262144; i += stride) {
        int j = i & 7, lane = (i >> 3) & 63, kt = (i >> 9) & 7;
        int gate = (i >> 12) & 3, g16 = i >> 14;
        int srow = gate * 256 + g16 * 16 + (lane & 15);
        int k = kt * 32 + ((lane >> 4) & 3) * 8 + j;
        p.WsS[i] = f2e4m3(p.rWih[srow * 256 + k] + p.rWhh[srow * 256 + k]);
      }
      break;
  }
}

// ---------------------------------------------------------------------------
// gemm_act: Y[1024,N] = act(X[1024,K] @ W^T + bias), stream-layout weights.
// ---------------------------------------------------------------------------
__global__ __launch_bounds__(256) void gemm_act(
    const u16* __restrict__ X, const u16* __restrict__ W,
    const float* __restrict__ bias,
    u16* __restrict__ Yb, float* __restrict__ Yf,
    int K, int ldo, int coloff, int leaky) {
  const int rt = blockIdx.x, ct = blockIdx.y;
  const int lane = threadIdx.x & 63, wave = threadIdx.x >> 6;
  const int m15 = lane & 15, q = lane >> 4, kq = q * 8;
  const int KT = K >> 5;
  const int row = rt * 64 + wave * 16 + m15;
  f32x4 acc[4] = {};
  const u16* xp = X + (size_t)row * K + kq;
  const u16* wst = W + lane * 8;
  for (int kt = 0; kt < KT; kt++) {
    bfrag a = *(const bfrag*)(xp + kt * 32);
#pragma unroll
    for (int nt = 0; nt < 4; nt++) {
      const u16* wp = wst + (size_t)((ct * 4 + nt) * KT + kt) * 512;
      acc[nt] = MFMA(a, *(const bfrag*)wp, acc[nt]);
    }
  }
#pragma unroll
  for (int nt = 0; nt < 4; nt++) {
    int col = ct * 64 + nt * 16 + m15;
    float bv = bias[col];
#pragma unroll
    for (int r = 0; r < 4; r++) {
      int orow = rt * 64 + wave * 16 + q * 4 + r;
      float v = acc[nt][r] + bv;
      if (leaky) v = v >= 0.f ? v : 0.2f * v;
      if (Yb) Yb[(size_t)orow * ldo + coloff + col] = f2b(v);
      else    Yf[(size_t)orow * ldo + coloff + col] = v;
    }
  }
}

// three independent gemms in one dispatch (blockIdx.z selects)
struct G3 {
  const u16 *X, *W;
  const float* bias;
  u16* Yb;
  float* Yf;
  int K, ldo, coloff, leaky;
};
__global__ __launch_bounds__(256) void gemm_act3(G3 ga, G3 gb, G3 gc) {
  G3 g = (blockIdx.z == 0) ? ga : (blockIdx.z == 1) ? gb : gc;
  const int rt = blockIdx.x, ct = blockIdx.y;
  const int lane = threadIdx.x & 63, wave = threadIdx.x >> 6;
  const int m15 = lane & 15, q = lane >> 4, kq = q * 8;
  const int KT = g.K >> 5;
  const int row = rt * 64 + wave * 16 + m15;
  f32x4 acc[4] = {};
  const u16* xp = g.X + (size_t)row * g.K + kq;
  const u16* wst = g.W + lane * 8;
  for (int kt = 0; kt < KT; kt++) {
    bfrag a = *(const bfrag*)(xp + kt * 32);
#pragma unroll
    for (int nt = 0; nt < 4; nt++) {
      const u16* wp = wst + (size_t)((ct * 4 + nt) * KT + kt) * 512;
      acc[nt] = MFMA(a, *(const bfrag*)wp, acc[nt]);
    }
  }
#pragma unroll
  for (int nt = 0; nt < 4; nt++) {
    int col = ct * 64 + nt * 16 + m15;
    float bv = g.bias[col];
#pragma unroll
    for (int r = 0; r < 4; r++) {
      int orow = rt * 64 + wave * 16 + q * 4 + r;
      float v = acc[nt][r] + bv;
      if (g.leaky) v = v >= 0.f ? v : 0.2f * v;
      if (g.Yb) g.Yb[(size_t)orow * g.ldo + g.coloff + col] = f2b(v);
      else      g.Yf[(size_t)orow * g.ldo + g.coloff + col] = v;
    }
  }
}

// ---------------------------------------------------------------------------
// decode_h v14: R6/R9's 242us steady loop (byte-identical), plus step 0
// folded in as a K=512 bf16 prologue (stream WcatR over [x0|h], c0 straight
// from the c-head gemm). No inter-block sync anywhere.
// Stream layout (harness-verified): lane (w,m15,q) writes its packed b32 at
// (w>>1)*512 + ((w&1)*2+(q>>1))*128 + m15*8 + (q&1)*4; frag read kt is
// lds[kt*512 + lane*8] (stride-1, conflict-free).
// ---------------------------------------------------------------------------
__global__ __attribute__((amdgpu_flat_work_group_size(1024, 1024), amdgpu_waves_per_eu(4, 4)))
void decode_h(
    const u8* __restrict__ WsS,     // [262144] fp8 decode weights (stream)
    const u16* __restrict__ WcatR,  // [1024][512] bf16 step-0 weights (stream)
    const float* __restrict__ rb,   // rbR [1024]
    const float* __restrict__ CB,   // [1024][256] c0 (fp32, from c-head gemm)
    const u16* __restrict__ X0H,    // [1024][512] bf16: cols 0-255 x0, 256-511 h
    u8* __restrict__ hG) {          // [64][128][4096] fp8 h stream (stream lay)
  __shared__ __align__(16) u8 hbufS[2][4096];   // 8 KB h ping-pong (stream)
  __shared__ __align__(16) u8 WoL[16][4096];    // 64 KB gate-o weights
  const int tid = threadIdx.x;
  const int w = tid >> 6, lane = tid & 63;
  const int m15 = lane & 15, q = lane >> 4;
  const int b = blockIdx.x;
  const int rowg = b * 16;

  // stage gate-o weights (stream slices) into LDS once
  {
    int4* dst = (int4*)WoL;
    for (int i = tid; i < 4096; i += 1024) {
      int wv = i >> 8, rest = i & 255;
      dst[i] = ((const int4*)(WsS + wv * 16384 + 12288))[rest];
    }
  }
  // biases: 16 pinned VGPRs, used as MFMA C-init (no per-step LDS reads)
  const float* rbp = rb + w * 64 + q * 4;
  f32x4 rbv0 = *(const f32x4*)(rbp +  0);
  f32x4 rbv1 = *(const f32x4*)(rbp + 16);
  f32x4 rbv2 = *(const f32x4*)(rbp + 32);
  f32x4 rbv3 = *(const f32x4*)(rbp + 48);
  asm volatile("" : "+v"(rbv0), "+v"(rbv1), "+v"(rbv2), "+v"(rbv3));
  // c0 straight from the c-head gemm; step 0 is computed here
  f32x4 cst = *(const f32x4*)(CB + (size_t)(rowg + m15) * 256 + w * 16 + q * 4);
  const int wroff = (w >> 1) * 512 + ((w & 1) * 2 + (q >> 1)) * 128 + m15 * 8 + (q & 1) * 4;
  u8* hGs = hG + (size_t)b * 524288 + wroff;

  // ---- prologue: step 0, K=512 over [x0 | h] with stream WcatR ----
  {
    f32x4 ai = rbv0, af_ = rbv1, ag = rbv2, ao = rbv3;
    const u16* xrow = X0H + (size_t)(rowg + m15) * 512 + q * 8;
    const u16* wcw = WcatR + (size_t)w * 32768 + lane * 8;
#pragma unroll
    for (int kt = 0; kt < 16; kt++) {
      bfrag a = *(const bfrag*)(xrow + kt * 32);
      ai  = MFMA(*(const bfrag*)(wcw + kt * 512), a, ai);
      af_ = MFMA(*(const bfrag*)(wcw + 8192 + kt * 512), a, af_);
      ag  = MFMA(*(const bfrag*)(wcw + 16384 + kt * 512), a, ag);
      ao  = MFMA(*(const bfrag*)(wcw + 24576 + kt * 512), a, ao);
    }
    float hn[4];
#pragma unroll
    for (int r = 0; r < 4; r++) {
      float2 hc2 = lstm2(ai[r], af_[r], ag[r], ao[r], cst[r]);
      hn[r] = hc2.x;
      cst[r] = hc2.y;
    }
    unsigned hv = pk4_e4m3(hn[0], hn[1], hn[2], hn[3]);
    *(unsigned*)(&hbufS[0][wroff]) = hv;
    *(unsigned*)hGs = hv;
  }
  // steady weights i/f/g resident: 24 frags = 48 AGPRs (loaded after the
  // bf16 prologue to keep its register pressure low)
  const u8* wsb = WsS + (size_t)w * 16384 + lane * 8;
  f8frag Wv0[8], Wv1[8], Wv2[8];
#pragma unroll
  for (int kt = 0; kt < 8; kt++) {
    Wv0[kt] = *(const f8frag*)(wsb + kt * 512);
    Wv1[kt] = *(const f8frag*)(wsb + 4096 + kt * 512);
    Wv2[kt] = *(const f8frag*)(wsb + 8192 + kt * 512);
  }
  PIN_A8(Wv0); PIN_A8(Wv1); PIN_A8(Wv2);
  const u8* woW = &WoL[w][lane * 8];
  __syncthreads();   // WoL + hbufS[0] complete

  for (int s = 1; s < 128; s++) {
    PIN_A8(Wv0); PIN_A8(Wv1); PIN_A8(Wv2);
    asm volatile("" : "+v"(rbv0), "+v"(rbv1), "+v"(rbv2), "+v"(rbv3));
    const u8* h8 = &hbufS[(s - 1) & 1][lane * 8];
    f32x4 ai = rbv0, af_ = rbv1, ag = rbv2, ao = rbv3;
#pragma unroll
    for (int kt = 0; kt < 8; kt++) {
      f8frag a8 = *(const f8frag*)(h8 + kt * 512);
      f8frag wo = *(const f8frag*)(woW + kt * 512);
      ai  = MFMA8(Wv0[kt], a8, ai);
      af_ = MFMA8(Wv1[kt], a8, af_);
      ag  = MFMA8(Wv2[kt], a8, ag);
      ao  = MFMA8(wo, a8, ao);
    }
    float hn[4];
#pragma unroll
    for (int r = 0; r < 4; r++) {
      float2 hc2 = lstm2(ai[r], af_[r], ag[r], ao[r], cst[r]);
      hn[r] = hc2.x;
      cst[r] = hc2.y;
    }
    unsigned hv = pk4_e4m3(hn[0], hn[1], hn[2], hn[3]);
    *(unsigned*)(&hbufS[s & 1][wroff]) = hv;
    *(unsigned*)(hGs + (size_t)s * 4096) = hv;
    LDS_BARRIER();   // hG store-acks float freely across steps
  }
}

// ---- pred_y: R6/R9 version (linear chunk stage, stream frags, fused softmax) ----
__global__ __launch_bounds__(512, 2) void pred_y(
    const u8* __restrict__ hG,      // [64][128][4096] stream layout
    const u8* __restrict__ pWsS,    // [32768] fp8 pred x-weights (stream)
    const u8* __restrict__ pWhhS,   // [4096] fp8 pred h-weights (stream)
    const float* __restrict__ pb,   // pbR [128]
    float* __restrict__ out) {      // [1024][128][32] final output
  __shared__ __align__(16) u8 stageL[16384];      // 16 KB = 4 steps of h
  __shared__ __align__(16) u8 hp8[2][16][40];
  __shared__ float ysC[4][16][36];
  const int tid = threadIdx.x;      // 0..511
  const int w = tid >> 6, lane = tid & 63;
  const int m15 = lane & 15, q = lane >> 4;
  const int b = blockIdx.x, rowg = b * 16;
  for (int i = tid; i < 2 * 16 * 40; i += 512) (&hp8[0][0][0])[i] = 0;
  // pred weights resident (18 VGPRs)
  const u8* pwsb = pWsS + (size_t)w * 4096 + lane * 8;
  f8frag pbv[8];
#pragma unroll
  for (int kt = 0; kt < 8; kt++) pbv[kt] = *(const f8frag*)(pwsb + kt * 512);
  f8frag phw = *(const f8frag*)(pWhhS + (size_t)w * 512 + lane * 8);
  PIN_V8(pbv);
  asm volatile("" : "+v"(phw));
  const f32x4 pbias = *(const f32x4*)(pb + w * 16 + q * 4);
  float cp = 0.f;
  const int4* hGb = (const int4*)(hG + (size_t)b * 524288);
  // fused-softmax task mapping: task t=tid>>3 -> (si=t>>4, r=t&15), sub=tid&7
  const int t_si = (tid >> 3) >> 4, t_r = (tid >> 3) & 15, sub = tid & 7;
  __syncthreads();

  for (int cs = 0; cs < 32; cs++) {
    // linear copy of 4 h-steps (16 KB) into LDS
    {
      int4* sdst = (int4*)stageL;
      sdst[tid] = hGb[cs * 1024 + tid];
      sdst[tid + 512] = hGb[cs * 1024 + tid + 512];
    }
    __syncthreads();   // waits the vmcnt-dependent LDS writes + all waves
#pragma unroll
    for (int si = 0; si < 4; si++) {
      const int s = cs * 4 + si;
      const u8* xr8 = &stageL[si * 4096 + lane * 8];
      f32x4 pacc = pbias;
#pragma unroll
      for (int kt = 0; kt < 8; kt++) {
        f8frag pav = *(const f8frag*)(xr8 + kt * 512);
        pacc = MFMA8(pbv[kt], pav, pacc);
      }
      f8frag pah = *(const f8frag*)(&hp8[s & 1][m15][q * 8]);
      pacc = MFMA8(phw, pah, pacc);
      // lane (m15,q) holds gates i,f,g,o of (batch m15, predcol w*4+q)
      float2 hc2 = lstm2(pacc[0], pacc[1], pacc[2], pacc[3], cp);
      cp = hc2.y;
      hp8[(s + 1) & 1][m15][w * 4 + q] = f2e4m3(hc2.x);
      ysC[si][m15][w * 4 + q] = hc2.x;
      LDS_BARRIER();
    }
    // fused softmax + sigmoid + final store for this chunk (4 steps)
    {
      f32x4 yv = *(const f32x4*)&ysC[t_si][t_r][sub * 4];
      float v3 = (sub == 7) ? -1e30f : yv[3];
      float m = fmaxf(fmaxf(yv[0], yv[1]), fmaxf(yv[2], v3));
#pragma unroll
      for (int off = 4; off; off >>= 1) m = fmaxf(m, __shfl_xor(m, off, 8));
      float e0 = __expf(yv[0] - m), e1 = __expf(yv[1] - m), e2 = __expf(yv[2] - m);
      float e3 = (sub == 7) ? 0.f : __expf(yv[3] - m);
      float tot = e0 + e1 + e2 + e3;
#pragma unroll
      for (int off = 4; off; off >>= 1) tot += __shfl_xor(tot, off, 8);
      float inv = rcp(tot);
      f32x4 o;
      o[0] = e0 * inv; o[1] = e1 * inv; o[2] = e2 * inv;
      o[3] = (sub == 7) ? ssig(yv[3]) : e3 * inv;
      *(f32x4*)(out + (size_t)(rowg + t_r) * 4096 + (cs * 4 + t_si) * 32 + sub * 4) = o;
    }
    LDS_BARRIER();   // ysC/stage consumed before next chunk overwrites
  }
}

// ---------------------------------------------------------------------------
extern "C" void kernel_launch(void* const* d_in, const int* in_sizes, int n_in,
                              void* d_out, int out_size, void* d_ws, size_t ws_size,
                              hipStream_t stream) {
  (void)in_sizes; (void)n_in; (void)out_size; (void)ws_size;
  const float* x    = (const float*)d_in[0];
  const float* W1   = (const float*)d_in[1];
  const float* b1   = (const float*)d_in[2];
  const float* W2   = (const float*)d_in[3];
  const float* b2   = (const float*)d_in[4];
  const float* W3   = (const float*)d_in[5];
  const float* b3   = (const float*)d_in[6];
  const float* Wh1  = (const float*)d_in[7];
  const float* bh1  = (const float*)d_in[8];
  const float* Wh2  = (const float*)d_in[9];
  const float* bh2  = (const float*)d_in[10];
  const float* Wc1  = (const float*)d_in[11];
  const float* bc1  = (const float*)d_in[12];
  const float* Wc2  = (const float*)d_in[13];
  const float* bc2  = (const float*)d_in[14];
  const float* Wx1  = (const float*)d_in[15];
  const float* bx1  = (const float*)d_in[16];
  const float* Wx2  = (const float*)d_in[17];
  const float* bx2  = (const float*)d_in[18];
  const float* rWih = (const float*)d_in[19];
  const float* rWhh = (const float*)d_in[20];
  const float* rbih = (const float*)d_in[21];
  const float* rbhh = (const float*)d_in[22];
  const float* pWih = (const float*)d_in[23];
  const float* pWhh = (const float*)d_in[24];
  const float* pbih = (const float*)d_in[25];
  const float* pbhh = (const float*)d_in[26];

  char* w = (char*)d_ws;
  auto alloc = [&](size_t bytes) -> char* {
    char* p = w;
    w += (bytes + 255) & ~(size_t)255;
    return p;
  };
  u16* Xbf  = (u16*)alloc(1024 * 128 * 2);
  u16* T1   = (u16*)alloc(1024 * 512 * 2);
  u16* T2   = (u16*)alloc(1024 * 512 * 2);
  u16* T3   = (u16*)alloc(1024 * 512 * 2);
  u16* TH   = (u16*)alloc(1024 * 512 * 2);
  u16* TC   = (u16*)alloc(1024 * 512 * 2);
  u16* TX   = (u16*)alloc(1024 * 512 * 2);
  u16* X0H  = (u16*)alloc(1024 * 512 * 2);  // cols 0..255 = x0, 256..511 = h
  float* CB = (float*)alloc(1024 * 256 * 4);
  u16* W1b  = (u16*)alloc(512 * 128 * 2);
  u16* W2b  = (u16*)alloc(512 * 512 * 2);
  u16* W3b  = (u16*)alloc(512 * 512 * 2);
  u16* Wh1b = (u16*)alloc(512 * 512 * 2);
  u16* Wc1b = (u16*)alloc(512 * 512 * 2);
  u16* Wx1b = (u16*)alloc(512 * 512 * 2);
  u16* Wh2b = (u16*)alloc(256 * 512 * 2);
  u16* Wc2b = (u16*)alloc(256 * 512 * 2);
  u16* Wx2b = (u16*)alloc(256 * 512 * 2);
  u16* WcatR= (u16*)alloc(1024 * 512 * 2);
  u8*  WsS  = (u8*)alloc(262144);
  u8*  pWsS = (u8*)alloc(32768);
  u8*  pWhhS= (u8*)alloc(4096);
  float* rbR = (float*)alloc(1024 * 4);
  float* pbR = (float*)alloc(128 * 4);
  u8*  hG   = (u8*)alloc((size_t)64 * 128 * 4096);   // 32 MB fp8 h stream

  PrepArgs pa;
  pa.x = x; pa.W1 = W1; pa.W2 = W2; pa.W3 = W3; pa.Wh1 = Wh1; pa.Wc1 = Wc1; pa.Wx1 = Wx1;
  pa.Wh2 = Wh2; pa.Wc2 = Wc2; pa.Wx2 = Wx2;
  pa.rWih = rWih; pa.rWhh = rWhh; pa.rbih = rbih; pa.rbhh = rbhh;
  pa.pWih = pWih; pa.pWhh = pWhh; pa.pbih = pbih; pa.pbhh = pbhh;
  pa.Xbf = Xbf; pa.W1b = W1b; pa.W2b = W2b; pa.W3b = W3b; pa.Wh1b = Wh1b;
  pa.Wc1b = Wc1b; pa.Wx1b = Wx1b; pa.Wh2b = Wh2b; pa.Wc2b = Wc2b; pa.Wx2b = Wx2b;
  pa.WcatR = WcatR;
  pa.WsS = WsS; pa.pWsS = pWsS; pa.pWhhS = pWhhS;
  pa.rbR = rbR; pa.pbR = pbR;
  prep<<<dim3(32, 16), 256, 0, stream>>>(pa);

  // MLP trunk
  gemm_act<<<dim3(16, 8), 256, 0, stream>>>(Xbf, W1b, b1, T1, nullptr, 128, 512, 0, 1);
  gemm_act<<<dim3(16, 8), 256, 0, stream>>>(T1, W2b, b2, T2, nullptr, 512, 512, 0, 1);
  gemm_act<<<dim3(16, 8), 256, 0, stream>>>(T2, W3b, b3, T3, nullptr, 512, 512, 0, 1);
  // heads layer 1 (3 gemms, one dispatch)
  G3 h1a = {T3, Wh1b, bh1, TH, nullptr, 512, 512, 0, 1};
  G3 h1b = {T3, Wc1b, bc1, TC, nullptr, 512, 512, 0, 1};
  G3 h1c = {T3, Wx1b, bx1, TX, nullptr, 512, 512, 0, 1};
  gemm_act3<<<dim3(16, 8, 3), 256, 0, stream>>>(h1a, h1b, h1c);
  // heads layer 2 (3 gemms, one dispatch)
  G3 h2a = {TH, Wh2b, bh2, X0H, nullptr, 512, 512, 256, 0};  // h -> X0H hi
  G3 h2b = {TC, Wc2b, bc2, nullptr, CB, 512, 256, 0, 0};     // c0 (fp32)
  G3 h2c = {TX, Wx2b, bx2, X0H, nullptr, 512, 512, 0, 0};    // x0 -> X0H lo
  gemm_act3<<<dim3(16, 4, 3), 256, 0, stream>>>(h2a, h2b, h2c);

  // decode (step0 prologue + 127 steps) -> pred (+fused softmax)
  decode_h<<<64, 1024, 0, stream>>>(WsS, WcatR, rbR, CB, X0H, hG);
  pred_y<<<64, 512, 0, stream>>>(hG, pWsS, pWhhS, pbR, (float*)d_out);
}